// Round 3
// baseline (901.940 us; speedup 1.0000x reference)
//
#include <hip/hip_runtime.h>
#include <hip/hip_bf16.h>
#include <math.h>

// ---------- types ----------
typedef __attribute__((ext_vector_type(8))) short   short8;
typedef __attribute__((ext_vector_type(4))) short   short4v;
typedef __attribute__((ext_vector_type(8))) __bf16  bf16x8;
typedef __attribute__((ext_vector_type(4))) float   f32x4;

__device__ __forceinline__ float bs2f(short s) {
  unsigned int u = ((unsigned int)(unsigned short)s) << 16;
  return __builtin_bit_cast(float, u);
}
__device__ __forceinline__ short f2bs(float f) {
  __hip_bfloat16 h = __float2bfloat16(f);  // RNE
  return __builtin_bit_cast(short, h);
}

// ---------- problem constants ----------
// B=4, S=1024, D=1024, H=8, FF=4096, DK=128. All I/O tensors are float32;
// internal GEMM operands are bf16, accumulation fp32.

// ---------- weight transpose + f32->bf16: out[C][R] = bf16(in[R][C]) ----------
__global__ __launch_bounds__(256) void transpose_k(const float* __restrict__ in,
                                                   short* __restrict__ out,
                                                   int R, int C) {
  __shared__ __align__(16) short T[64 * 72];
  const int r0 = blockIdx.y * 64, c0 = blockIdx.x * 64;
  const int t = threadIdx.x;
  {
    const int rr = t >> 4;           // 0..15
    const int cc = (t & 15) << 2;    // 0..60 step 4
#pragma unroll
    for (int h = 0; h < 4; h++) {
      const int row = rr + h * 16;
      f32x4 v = *(const f32x4*)(in + (long)(r0 + row) * C + c0 + cc);
#pragma unroll
      for (int e = 0; e < 4; e++) T[row * 72 + cc + e] = f2bs(v[e]);
    }
  }
  __syncthreads();
  {
    const int cr = t >> 3;           // 0..31
    const int rs = (t & 7) << 3;     // 0..56 step 8
#pragma unroll
    for (int h = 0; h < 2; h++) {
      const int c = cr + h * 32;
      short8 v;
#pragma unroll
      for (int e = 0; e < 8; e++) v[e] = T[(rs + e) * 72 + c];
      *(short8*)(out + (long)(c0 + c) * R + r0 + rs) = v;
    }
  }
}

// ---------- layernorm over rows of 1024; f32 input/params; bf16 output ----------
__global__ __launch_bounds__(256) void ln_k(const float* __restrict__ in,
                                            const float* __restrict__ g,
                                            const float* __restrict__ b,
                                            short* __restrict__ out) {
  const int t = threadIdx.x;
  const long base = (long)blockIdx.x * 1024 + t * 4;
  f32x4 f = *(const f32x4*)(in + base);
  float v[4] = {f[0], f[1], f[2], f[3]};
  float s1 = v[0] + v[1] + v[2] + v[3];
  float s2 = v[0]*v[0] + v[1]*v[1] + v[2]*v[2] + v[3]*v[3];
#pragma unroll
  for (int off = 32; off; off >>= 1) {
    s1 += __shfl_xor(s1, off);
    s2 += __shfl_xor(s2, off);
  }
  __shared__ float rs[4], rq[4];
  if ((t & 63) == 0) { rs[t >> 6] = s1; rq[t >> 6] = s2; }
  __syncthreads();
  s1 = rs[0] + rs[1] + rs[2] + rs[3];
  s2 = rq[0] + rq[1] + rq[2] + rq[3];
  const float mean = s1 * (1.0f / 1024.0f);
  const float var  = s2 * (1.0f / 1024.0f) - mean * mean;
  const float rstd = rsqrtf(var + 1e-5f);
  f32x4 gv = *(const f32x4*)(g + t * 4);
  f32x4 bv = *(const f32x4*)(b + t * 4);
  short4v o;
#pragma unroll
  for (int i = 0; i < 4; i++)
    o[i] = f2bs((v[i] - mean) * rstd * gv[i] + bv[i]);
  *(short4v*)(out + base) = o;
}

// ---------- softmax over rows of 1024 (bf16 in-place) ----------
__global__ __launch_bounds__(256) void softmax_k(short* __restrict__ sc) {
  const int t = threadIdx.x;
  const long base = (long)blockIdx.x * 1024 + t * 4;
  short4v sv = *(const short4v*)(sc + base);
  float v[4];
#pragma unroll
  for (int i = 0; i < 4; i++) v[i] = bs2f(sv[i]);
  float m = fmaxf(fmaxf(v[0], v[1]), fmaxf(v[2], v[3]));
#pragma unroll
  for (int off = 32; off; off >>= 1) m = fmaxf(m, __shfl_xor(m, off));
  __shared__ float red[4];
  if ((t & 63) == 0) red[t >> 6] = m;
  __syncthreads();
  m = fmaxf(fmaxf(red[0], red[1]), fmaxf(red[2], red[3]));
  float e[4], s = 0.0f;
#pragma unroll
  for (int i = 0; i < 4; i++) { e[i] = expf(v[i] - m); s += e[i]; }
#pragma unroll
  for (int off = 32; off; off >>= 1) s += __shfl_xor(s, off);
  __shared__ float red2[4];
  if ((t & 63) == 0) red2[t >> 6] = s;
  __syncthreads();
  s = red2[0] + red2[1] + red2[2] + red2[3];
  const float inv = 1.0f / s;
  short4v o;
#pragma unroll
  for (int i = 0; i < 4; i++) o[i] = f2bs(e[i] * inv);
  *(short4v*)(sc + base) = o;
}

// ---------- generic MFMA GEMM: C[m][n] = sum_k A[m][k] * Bt[n][k]  ----------
// 64x64 tile, BK=32, 256 threads (4 waves). blockIdx.z selects a slice at
// offset z*azl (A), z*bzl (B), z*czl (C). zoff: chunk base for VT/SUM8 dests.
enum { EPI_BIAS = 0, EPI_SCALE = 1, EPI_VT = 2, EPI_SUM8 = 3, EPI_GELU = 4, EPI_FFN2 = 5 };

template <int EPI>
__global__ __launch_bounds__(256) void gemm_nk(
    const short* __restrict__ A, int lda, long azl,
    const short* __restrict__ Bt, int ldb, long bzl,
    const float* __restrict__ bias,
    void* __restrict__ outp, long czl, int ldc,
    const void* __restrict__ aux,
    int K, float scale, int zoff) {
  const int t = threadIdx.x;
  const int wave = t >> 6, lane = t & 63;
  const int llo = lane & 15, lhi = lane >> 4;
  const int bn0 = blockIdx.x * 64, bm0 = blockIdx.y * 64;
  const int z = blockIdx.z;

  const short* Ab = A + (long)z * azl;
  const short* Bb = Bt + (long)z * bzl;

  __shared__ __align__(16) short smem[5120];
  short* As = smem;          // 64 x 40
  short* Bs = smem + 2560;   // 64 x 40

  f32x4 acc[4];
#pragma unroll
  for (int i = 0; i < 4; i++) acc[i] = f32x4{0.f, 0.f, 0.f, 0.f};

  const int sm = t >> 2;          // 0..63
  const int sk = (t & 3) << 3;    // 0,8,16,24
  const short* Ag = Ab + (long)(bm0 + sm) * lda + sk;
  const short* Bg = Bb + (long)(bn0 + sm) * ldb + sk;
  short* AsW = &As[sm * 40 + sk];
  short* BsW = &Bs[sm * 40 + sk];
  const short* aRd = &As[llo * 40 + lhi * 8];
  const short* bRd = &Bs[(wave * 16 + llo) * 40 + lhi * 8];

  for (int kt = 0; kt < K; kt += 32) {
    short8 av = *(const short8*)(Ag + kt);
    short8 bv = *(const short8*)(Bg + kt);
    *(short8*)AsW = av;
    *(short8*)BsW = bv;
    __syncthreads();
    bf16x8 bfrag = *(const bf16x8*)bRd;
#pragma unroll
    for (int rt = 0; rt < 4; rt++) {
      bf16x8 afrag = *(const bf16x8*)(aRd + rt * 16 * 40);
      acc[rt] = __builtin_amdgcn_mfma_f32_16x16x32_bf16(afrag, bfrag, acc[rt], 0, 0, 0);
    }
    __syncthreads();
  }

  const int colw = bn0 + wave * 16 + llo;

  if (EPI == EPI_BIAS || EPI == EPI_SCALE || EPI == EPI_GELU) {
    // bf16 outputs (internal buffers)
    short* C = (short*)outp + (long)z * czl;
    const float bval = (EPI == EPI_SCALE) ? 0.0f : bias[colw];
#pragma unroll
    for (int rt = 0; rt < 4; rt++) {
#pragma unroll
      for (int r = 0; r < 4; r++) {
        const int row = bm0 + rt * 16 + lhi * 4 + r;
        float v = acc[rt][r];
        if (EPI == EPI_SCALE) v *= scale;
        else v += bval;
        if (EPI == EPI_GELU) v = 0.5f * v * (1.0f + erff(v * 0.70710678118654752f));
        C[(long)row * ldc + colw] = f2bs(v);
      }
    }
  } else if (EPI == EPI_FFN2) {
    // f32 final output: v + bias + x1 residual
    float* C = (float*)outp;
    const float* x1p = (const float*)aux;
    const float bval = bias[colw];
#pragma unroll
    for (int rt = 0; rt < 4; rt++) {
#pragma unroll
      for (int r = 0; r < 4; r++) {
        const int row = bm0 + rt * 16 + lhi * 4 + r;
        C[(long)row * ldc + colw] = acc[rt][r] + bval + x1p[(long)row * ldc + colw];
      }
    }
  } else if (EPI == EPI_VT) {
    // A rows are s (one batch chunk), cols are h*1024+d. Write
    // VT[(zoff+h)][d][s] via LDS transpose bounce.
    __syncthreads();
    short* Ts = smem;  // Ts[col][row], stride 72
    const float bval = bias[colw];
#pragma unroll
    for (int rt = 0; rt < 4; rt++) {
#pragma unroll
      for (int r = 0; r < 4; r++) {
        const int row = rt * 16 + lhi * 4 + r;
        Ts[(wave * 16 + llo) * 72 + row] = f2bs(acc[rt][r] + bval);
      }
    }
    __syncthreads();
    const int s0 = bm0;
    const int hh = bn0 >> 10, d0 = bn0 & 1023;
    const int c = t >> 2, r0p = (t & 3) << 4;
    short* dst = (short*)outp + ((long)(zoff + hh) << 20) + (long)(d0 + c) * 1024 + s0 + r0p;
    const short* src = &Ts[c * 72 + r0p];
    short8 v0 = *(const short8*)src;
    short8 v1 = *(const short8*)(src + 8);
    *(short8*)dst = v0;
    *(short8*)(dst + 8) = v1;
  } else if (EPI == EPI_SUM8) {
    // attn_flat[g] = sum of 8 consecutive d of ctx row (z=h); x1[g]=x[g]+attn[g]
    const float* xg = (const float*)aux;  // FULL x base (f32)
    float* x1 = (float*)outp;             // FULL x1 base
#pragma unroll
    for (int rt = 0; rt < 4; rt++) {
#pragma unroll
      for (int r = 0; r < 4; r++) {
        float v = acc[rt][r];
        v += __shfl_xor(v, 1);
        v += __shfl_xor(v, 2);
        v += __shfl_xor(v, 4);
        if ((lane & 7) == 0) {
          const int row = bm0 + rt * 16 + lhi * 4 + r;
          const long rfull = (long)(zoff + z) * 1024 + row;
          const long g = rfull * 128 + ((bn0 + wave * 16 + (lane & 8)) >> 3);
          x1[g] = xg[g] + v;
        }
      }
    }
  }
}

// ---------- launch ----------
extern "C" void kernel_launch(void* const* d_in, const int* in_sizes, int n_in,
                              void* d_out, int out_size, void* d_ws, size_t ws_size,
                              hipStream_t stream) {
  const float* x   = (const float*)d_in[0];
  // d_in[1] = mask (int32) — unused in infer path
  const float* g1  = (const float*)d_in[2];
  const float* b1  = (const float*)d_in[3];
  const float* Wq  = (const float*)d_in[4];
  const float* bq  = (const float*)d_in[5];
  const float* Wk  = (const float*)d_in[6];
  const float* bk  = (const float*)d_in[7];
  const float* Wv  = (const float*)d_in[8];
  const float* bv  = (const float*)d_in[9];
  const float* g2  = (const float*)d_in[10];
  const float* b2  = (const float*)d_in[11];
  const float* W1  = (const float*)d_in[12];
  const float* bw1 = (const float*)d_in[13];
  const float* W2  = (const float*)d_in[14];
  const float* bw2 = (const float*)d_in[15];

  char* ws = (char*)d_ws;
  const long MB = 1024 * 1024;
  // ---- phase A (attention), peak 74MB ----
  float* x1  = (float*)(ws);             // [4096,1024] f32, 16MB, live to end
  short* wqT = (short*)(ws + 16 * MB);   // [1024,1024] bf16  2MB
  short* wkT = (short*)(ws + 18 * MB);   // [1024,1024] bf16  2MB
  short* wvT = (short*)(ws + 20 * MB);   // [8192,1024] bf16 16MB
  short* xnb = (short*)(ws + 36 * MB);   // [1024,1024]  2MB (per-b)
  short* Qb  = (short*)(ws + 38 * MB);   // [1024,1024]  2MB (per-b)
  short* Kbb = (short*)(ws + 40 * MB);   // [1024,1024]  2MB (per-b)
  short* VTb = (short*)(ws + 42 * MB);   // [8,1024,1024] 16MB (per-b)
  short* Scb = (short*)(ws + 58 * MB);   // [8,1024,1024] 16MB (per-b) → 74MB
  // ---- phase B (FFN), overlays 16..72MB after attention ----
  short* xn2 = (short*)(ws + 16 * MB);   // [4096,1024]  8MB
  short* Hb  = (short*)(ws + 24 * MB);   // [4096,4096] 32MB
  short* w1T = (short*)(ws + 56 * MB);   // [4096,1024]  8MB
  short* w2T = (short*)(ws + 64 * MB);   // [1024,4096]  8MB → 72MB

  // QKV weight transposes to bf16 [N,K]
  transpose_k<<<dim3(16, 16), 256, 0, stream>>>(Wq, wqT, 1024, 1024);
  transpose_k<<<dim3(16, 16), 256, 0, stream>>>(Wk, wkT, 1024, 1024);
  transpose_k<<<dim3(128, 16), 256, 0, stream>>>(Wv, wvT, 1024, 8192);

  for (int b = 0; b < 4; b++) {
    const float* xb = x + (long)b * 1048576;
    // LN1 for this batch's 1024 rows -> bf16
    ln_k<<<1024, 256, 0, stream>>>(xb, g1, b1, xnb);
    // Q, K projections [1024,1024]
    gemm_nk<EPI_BIAS><<<dim3(16, 16, 1), 256, 0, stream>>>(
        xnb, 1024, 0, wqT, 1024, 0, bq, Qb, 0, 1024, nullptr, 1024, 1.0f, 0);
    gemm_nk<EPI_BIAS><<<dim3(16, 16, 1), 256, 0, stream>>>(
        xnb, 1024, 0, wkT, 1024, 0, bk, Kbb, 0, 1024, nullptr, 1024, 1.0f, 0);
    // V projection, stored transposed per head: VTb[h][d][s]
    gemm_nk<EPI_VT><<<dim3(128, 16, 1), 256, 0, stream>>>(
        xnb, 1024, 0, wvT, 1024, 0, bv, VTb, 0, 0, nullptr, 1024, 1.0f, 0);
    // scores = Q K^T / sqrt(128), z = h
    gemm_nk<EPI_SCALE><<<dim3(16, 16, 8), 256, 0, stream>>>(
        Qb, 1024, 128, Kbb, 1024, 128, nullptr,
        Scb, 1048576, 1024, nullptr, 128, 0.0883883476483184f, 0);
    // softmax rows
    softmax_k<<<8192, 256, 0, stream>>>(Scb);
    // ctx = P @ V fused consecutive-8 head-sum + residual -> x1 (f32, full)
    gemm_nk<EPI_SUM8><<<dim3(16, 16, 8), 256, 0, stream>>>(
        Scb, 1024, 1048576, VTb, 1024, 1048576, nullptr,
        x1, 0, 0, x, 1024, 1.0f, b * 8);
  }

  // FFN weight transposes (deferred so they can overlay attention scratch)
  transpose_k<<<dim3(64, 16), 256, 0, stream>>>(W1, w1T, 1024, 4096);
  transpose_k<<<dim3(16, 64), 256, 0, stream>>>(W2, w2T, 4096, 1024);

  // LN2 over full x1 -> bf16
  ln_k<<<4096, 256, 0, stream>>>(x1, g2, b2, xn2);

  // FFN1 + exact GELU -> bf16 Hb
  gemm_nk<EPI_GELU><<<dim3(64, 64, 1), 256, 0, stream>>>(
      xn2, 1024, 0, w1T, 1024, 0, bw1, Hb, 0, 4096, nullptr, 1024, 1.0f, 0);

  // FFN2 + bias + residual(x1) -> d_out (f32)
  gemm_nk<EPI_FFN2><<<dim3(16, 64, 1), 256, 0, stream>>>(
      Hb, 4096, 0, w2T, 4096, 0, bw2, d_out, 0, 1024, x1, 4096, 1.0f, 0);
}

// Round 4
// 779.569 us; speedup vs baseline: 1.1570x; 1.1570x over previous
//
#include <hip/hip_runtime.h>
#include <hip/hip_bf16.h>
#include <math.h>

// ---------- types ----------
typedef __attribute__((ext_vector_type(8))) short   short8;
typedef __attribute__((ext_vector_type(4))) short   short4v;
typedef __attribute__((ext_vector_type(8))) __bf16  bf16x8;
typedef __attribute__((ext_vector_type(4))) float   f32x4;

typedef const __attribute__((address_space(1))) void cgv_t;
typedef __attribute__((address_space(3))) void lv_t;

__device__ __forceinline__ float bs2f(short s) {
  unsigned int u = ((unsigned int)(unsigned short)s) << 16;
  return __builtin_bit_cast(float, u);
}
__device__ __forceinline__ short f2bs(float f) {
  __hip_bfloat16 h = __float2bfloat16(f);  // RNE
  return __builtin_bit_cast(short, h);
}
// async global->LDS, 16B per lane; lds base must be wave-uniform
__device__ __forceinline__ void glds16(const short* g, short* l) {
  __builtin_amdgcn_global_load_lds((cgv_t*)g, (lv_t*)l, 16, 0, 0);
}

// ---------- problem constants ----------
// B=4, S=1024, D=1024, H=8, FF=4096, DK=128. I/O f32; internals bf16.

// ---------- weight transpose + f32->bf16: out[C][R] = bf16(in[R][C]) ----------
__global__ __launch_bounds__(256) void transpose_k(const float* __restrict__ in,
                                                   short* __restrict__ out,
                                                   int R, int C) {
  __shared__ __align__(16) short T[64 * 72];
  const int r0 = blockIdx.y * 64, c0 = blockIdx.x * 64;
  const int t = threadIdx.x;
  {
    const int rr = t >> 4;           // 0..15
    const int cc = (t & 15) << 2;    // 0..60 step 4
#pragma unroll
    for (int h = 0; h < 4; h++) {
      const int row = rr + h * 16;
      f32x4 v = *(const f32x4*)(in + (long)(r0 + row) * C + c0 + cc);
#pragma unroll
      for (int e = 0; e < 4; e++) T[row * 72 + cc + e] = f2bs(v[e]);
    }
  }
  __syncthreads();
  {
    const int cr = t >> 3;           // 0..31
    const int rs = (t & 7) << 3;     // 0..56 step 8
#pragma unroll
    for (int h = 0; h < 2; h++) {
      const int c = cr + h * 32;
      short8 v;
#pragma unroll
      for (int e = 0; e < 8; e++) v[e] = T[(rs + e) * 72 + c];
      *(short8*)(out + (long)(c0 + c) * R + r0 + rs) = v;
    }
  }
}

// ---------- layernorm rows of 1024; f32 in/params; bf16 out ----------
__global__ __launch_bounds__(256) void ln_k(const float* __restrict__ in,
                                            const float* __restrict__ g,
                                            const float* __restrict__ b,
                                            short* __restrict__ out) {
  const int t = threadIdx.x;
  const long base = (long)blockIdx.x * 1024 + t * 4;
  f32x4 f = *(const f32x4*)(in + base);
  float v[4] = {f[0], f[1], f[2], f[3]};
  float s1 = v[0] + v[1] + v[2] + v[3];
  float s2 = v[0]*v[0] + v[1]*v[1] + v[2]*v[2] + v[3]*v[3];
#pragma unroll
  for (int off = 32; off; off >>= 1) {
    s1 += __shfl_xor(s1, off);
    s2 += __shfl_xor(s2, off);
  }
  __shared__ float rs[4], rq[4];
  if ((t & 63) == 0) { rs[t >> 6] = s1; rq[t >> 6] = s2; }
  __syncthreads();
  s1 = rs[0] + rs[1] + rs[2] + rs[3];
  s2 = rq[0] + rq[1] + rq[2] + rq[3];
  const float mean = s1 * (1.0f / 1024.0f);
  const float var  = s2 * (1.0f / 1024.0f) - mean * mean;
  const float rstd = rsqrtf(var + 1e-5f);
  f32x4 gv = *(const f32x4*)(g + t * 4);
  f32x4 bv = *(const f32x4*)(b + t * 4);
  short4v o;
#pragma unroll
  for (int i = 0; i < 4; i++)
    o[i] = f2bs((v[i] - mean) * rstd * gv[i] + bv[i]);
  *(short4v*)(out + base) = o;
}

// ---------- softmax rows of 1024 (bf16 in-place) ----------
__global__ __launch_bounds__(256) void softmax_k(short* __restrict__ sc) {
  const int t = threadIdx.x;
  const long base = (long)blockIdx.x * 1024 + t * 4;
  short4v sv = *(const short4v*)(sc + base);
  float v[4];
#pragma unroll
  for (int i = 0; i < 4; i++) v[i] = bs2f(sv[i]);
  float m = fmaxf(fmaxf(v[0], v[1]), fmaxf(v[2], v[3]));
#pragma unroll
  for (int off = 32; off; off >>= 1) m = fmaxf(m, __shfl_xor(m, off));
  __shared__ float red[4];
  if ((t & 63) == 0) red[t >> 6] = m;
  __syncthreads();
  m = fmaxf(fmaxf(red[0], red[1]), fmaxf(red[2], red[3]));
  float e[4], s = 0.0f;
#pragma unroll
  for (int i = 0; i < 4; i++) { e[i] = expf(v[i] - m); s += e[i]; }
#pragma unroll
  for (int off = 32; off; off >>= 1) s += __shfl_xor(s, off);
  __shared__ float red2[4];
  if ((t & 63) == 0) red2[t >> 6] = s;
  __syncthreads();
  s = red2[0] + red2[1] + red2[2] + red2[3];
  const float inv = 1.0f / s;
  short4v o;
#pragma unroll
  for (int i = 0; i < 4; i++) o[i] = f2bs(e[i] * inv);
  *(short4v*)(sc + base) = o;
}

// ---------- 128x128 MFMA GEMM (m97 structure): C[m][n] = sum_k A[m][k]*Bt[n][k]
// 256 threads = 4 waves in 2x2; BK=32; global_load_lds width-16 staging.
enum { EPI_BIAS = 0, EPI_SCALE = 1, EPI_VT = 2, EPI_SUM8 = 3, EPI_GELU = 4, EPI_FFN2 = 5 };

template <int EPI>
__global__ __launch_bounds__(256) void gemm128(
    const short* __restrict__ A, int lda, long azl,
    const short* __restrict__ Bt, int ldb, long bzl,
    const float* __restrict__ bias,
    void* __restrict__ outp, long czl, int ldc,
    const void* __restrict__ aux,
    int K, float scale, int zoff) {
  constexpr int SMEM_SHORTS = (EPI == EPI_VT) ? 17408 : 8192;
  __shared__ __align__(16) short smem[SMEM_SHORTS];
  short* As = smem;          // [128][32] unpadded (global_load_lds layout)
  short* Bs = smem + 4096;   // [128][32]

  const int t = threadIdx.x;
  const int wave = t >> 6, lane = t & 63;
  const int llo = lane & 15, lhi = lane >> 4;
  const int wm = wave >> 1, wn = wave & 1;
  const int bn0 = blockIdx.x * 128, bm0 = blockIdx.y * 128;
  const int z = blockIdx.z;

  const short* Ab = A + (long)z * azl;
  const short* Bb = Bt + (long)z * bzl;

  f32x4 acc[4][4];
#pragma unroll
  for (int i = 0; i < 4; i++)
#pragma unroll
    for (int j = 0; j < 4; j++) acc[i][j] = f32x4{0.f, 0.f, 0.f, 0.f};

  // staging: thread t loads 16B at row (t>>2), shorts offset (t&3)*8.
  const int srow = t >> 2, schunk = (t & 3) << 3;
  const short* Ag0 = Ab + (long)(bm0 + srow) * lda + schunk;
  const short* Ag1 = Ab + (long)(bm0 + 64 + srow) * lda + schunk;
  const short* Bg0 = Bb + (long)(bn0 + srow) * ldb + schunk;
  const short* Bg1 = Bb + (long)(bn0 + 64 + srow) * ldb + schunk;
  short* AsW0 = As + (wave * 16) * 32;        // wave-uniform bases
  short* AsW1 = As + (64 + wave * 16) * 32;
  short* BsW0 = Bs + (wave * 16) * 32;
  short* BsW1 = Bs + (64 + wave * 16) * 32;

  const short* aRd = As + (wm * 64 + llo) * 32 + lhi * 8;
  const short* bRd = Bs + (wn * 64 + llo) * 32 + lhi * 8;

  for (int kt = 0; kt < K; kt += 32) {
    glds16(Ag0 + kt, AsW0);
    glds16(Ag1 + kt, AsW1);
    glds16(Bg0 + kt, BsW0);
    glds16(Bg1 + kt, BsW1);
    __syncthreads();   // drains vmcnt(0): LDS tiles ready
    bf16x8 af[4], bf[4];
#pragma unroll
    for (int i = 0; i < 4; i++) {
      af[i] = *(const bf16x8*)(aRd + i * 16 * 32);
      bf[i] = *(const bf16x8*)(bRd + i * 16 * 32);
    }
#pragma unroll
    for (int rt = 0; rt < 4; rt++)
#pragma unroll
      for (int ct = 0; ct < 4; ct++)
        acc[rt][ct] = __builtin_amdgcn_mfma_f32_16x16x32_bf16(af[rt], bf[ct], acc[rt][ct], 0, 0, 0);
    __syncthreads();   // protect LDS before next staging round
  }

  if (EPI == EPI_BIAS || EPI == EPI_SCALE || EPI == EPI_GELU) {
    short* C = (short*)outp + (long)z * czl;
#pragma unroll
    for (int ct = 0; ct < 4; ct++) {
      const int col = bn0 + wn * 64 + ct * 16 + llo;
      const float bval = (EPI == EPI_SCALE) ? 0.0f : bias[col];
#pragma unroll
      for (int rt = 0; rt < 4; rt++) {
#pragma unroll
        for (int r = 0; r < 4; r++) {
          const int row = bm0 + wm * 64 + rt * 16 + lhi * 4 + r;
          float v = acc[rt][ct][r];
          if (EPI == EPI_SCALE) v *= scale;
          else v += bval;
          if (EPI == EPI_GELU) v = 0.5f * v * (1.0f + erff(v * 0.70710678118654752f));
          C[(long)row * ldc + col] = f2bs(v);
        }
      }
    }
  } else if (EPI == EPI_FFN2) {
    float* C = (float*)outp;
    const float* x1p = (const float*)aux;
#pragma unroll
    for (int ct = 0; ct < 4; ct++) {
      const int col = bn0 + wn * 64 + ct * 16 + llo;
      const float bval = bias[col];
#pragma unroll
      for (int rt = 0; rt < 4; rt++) {
#pragma unroll
        for (int r = 0; r < 4; r++) {
          const int row = bm0 + wm * 64 + rt * 16 + lhi * 4 + r;
          C[(long)row * ldc + col] = acc[rt][ct][r] + bval + x1p[(long)row * ldc + col];
        }
      }
    }
  } else if (EPI == EPI_VT) {
    // tile rows = s (per-batch), cols = h*1024+d; write VT[(zoff+h)][d][s]
    short* Ts = smem;  // [col][row], stride 136
#pragma unroll
    for (int ct = 0; ct < 4; ct++) {
      const int c = wn * 64 + ct * 16 + llo;
      const float bval = bias[bn0 + c];
#pragma unroll
      for (int rt = 0; rt < 4; rt++) {
#pragma unroll
        for (int r = 0; r < 4; r++) {
          const int row = wm * 64 + rt * 16 + lhi * 4 + r;
          Ts[c * 136 + row] = f2bs(acc[rt][ct][r] + bval);
        }
      }
    }
    __syncthreads();
    const int hh = bn0 >> 10, d0 = bn0 & 1023;
    short* dstbase = (short*)outp + ((long)(zoff + hh) << 20) + (long)d0 * 1024 + bm0;
    const int sc8 = (t & 15) << 3;    // s-chunk (8 shorts)
    const int cb = t >> 4;            // 0..15
#pragma unroll
    for (int j = 0; j < 8; j++) {
      const int c = cb + j * 16;
      *(short8*)(dstbase + (long)c * 1024 + sc8) = *(const short8*)&Ts[c * 136 + sc8];
    }
  } else if (EPI == EPI_SUM8) {
    // attn_flat[g] = sum of 8 consecutive d of ctx row (z=h); x1[g]=x[g]+attn[g]
    const float* xg = (const float*)aux;  // FULL x (f32)
    float* x1 = (float*)outp;             // FULL x1
#pragma unroll
    for (int ct = 0; ct < 4; ct++) {
      const int colg = bn0 + wn * 64 + ct * 16 + (lane & 8);
#pragma unroll
      for (int rt = 0; rt < 4; rt++) {
#pragma unroll
        for (int r = 0; r < 4; r++) {
          float v = acc[rt][ct][r];
          v += __shfl_xor(v, 1);
          v += __shfl_xor(v, 2);
          v += __shfl_xor(v, 4);
          if ((lane & 7) == 0) {
            const int row = bm0 + wm * 64 + rt * 16 + lhi * 4 + r;
            const long g = ((long)(zoff + z) * 1024 + row) * 128 + (colg >> 3);
            x1[g] = xg[g] + v;
          }
        }
      }
    }
  }
}

// ---------- launch ----------
extern "C" void kernel_launch(void* const* d_in, const int* in_sizes, int n_in,
                              void* d_out, int out_size, void* d_ws, size_t ws_size,
                              hipStream_t stream) {
  const float* x   = (const float*)d_in[0];
  // d_in[1] = mask (int32) — unused in infer path
  const float* g1  = (const float*)d_in[2];
  const float* b1  = (const float*)d_in[3];
  const float* Wq  = (const float*)d_in[4];
  const float* bq  = (const float*)d_in[5];
  const float* Wk  = (const float*)d_in[6];
  const float* bk  = (const float*)d_in[7];
  const float* Wv  = (const float*)d_in[8];
  const float* bv  = (const float*)d_in[9];
  const float* g2  = (const float*)d_in[10];
  const float* b2  = (const float*)d_in[11];
  const float* W1  = (const float*)d_in[12];
  const float* bw1 = (const float*)d_in[13];
  const float* W2  = (const float*)d_in[14];
  const float* bw2 = (const float*)d_in[15];

  char* ws = (char*)d_ws;
  const long MB = 1024 * 1024;
  const bool big = ws_size >= (size_t)(92 * MB);

  // common: x1 f32 at 0 (16MB, live to end); FFN overlays at [16,76)
  float* x1  = (float*)(ws);
  short* xn2 = (short*)(ws + 16 * MB);   // [4096,1024] bf16  8MB
  short* Hb  = (short*)(ws + 24 * MB);   // [4096,4096] bf16 32MB
  short* w1T = (short*)(ws + 56 * MB);   // [4096,1024]  8MB
  short* w2T = (short*)(ws + 64 * MB);   // [1024,4096]  8MB -> 72MB

  if (big) {
    // ---- 92MB layout: full xn/Q/K; per-batch VT/Sc ----
    short* wqT = (short*)(ws + 16 * MB);  // 2MB (dead before FFN overlay use)
    short* wkT = (short*)(ws + 18 * MB);  // 2MB
    short* wvT = (short*)(ws + 20 * MB);  // 16MB
    short* xn  = (short*)(ws + 36 * MB);  // [4096,1024] 8MB
    short* Q   = (short*)(ws + 44 * MB);  // 8MB
    short* Kb  = (short*)(ws + 52 * MB);  // 8MB
    short* VTb = (short*)(ws + 60 * MB);  // [8,1024,1024] 16MB per batch
    short* Scb = (short*)(ws + 76 * MB);  // 16MB per batch -> 92MB

    transpose_k<<<dim3(16, 16), 256, 0, stream>>>(Wq, wqT, 1024, 1024);
    transpose_k<<<dim3(16, 16), 256, 0, stream>>>(Wk, wkT, 1024, 1024);
    transpose_k<<<dim3(128, 16), 256, 0, stream>>>(Wv, wvT, 1024, 8192);

    ln_k<<<4096, 256, 0, stream>>>(x, g1, b1, xn);
    gemm128<EPI_BIAS><<<dim3(8, 32, 1), 256, 0, stream>>>(
        xn, 1024, 0, wqT, 1024, 0, bq, Q, 0, 1024, nullptr, 1024, 1.0f, 0);
    gemm128<EPI_BIAS><<<dim3(8, 32, 1), 256, 0, stream>>>(
        xn, 1024, 0, wkT, 1024, 0, bk, Kb, 0, 1024, nullptr, 1024, 1.0f, 0);

    for (int b = 0; b < 4; b++) {
      gemm128<EPI_VT><<<dim3(64, 8, 1), 256, 0, stream>>>(
          xn + (long)b * 1048576, 1024, 0, wvT, 1024, 0, bv, VTb, 0, 0,
          nullptr, 1024, 1.0f, 0);
      gemm128<EPI_SCALE><<<dim3(8, 8, 8), 256, 0, stream>>>(
          Q + (long)b * 1048576, 1024, 128, Kb + (long)b * 1048576, 1024, 128,
          nullptr, Scb, 1048576, 1024, nullptr, 128, 0.0883883476483184f, 0);
      softmax_k<<<8192, 256, 0, stream>>>(Scb);
      gemm128<EPI_SUM8><<<dim3(8, 8, 8), 256, 0, stream>>>(
          Scb, 1024, 1048576, VTb, 1024, 1048576, nullptr,
          x1, 0, 0, x, 1024, 1.0f, b * 8);
    }
  } else {
    // ---- proven 74MB fallback: per-batch everything ----
    short* wqT = (short*)(ws + 16 * MB);
    short* wkT = (short*)(ws + 18 * MB);
    short* wvT = (short*)(ws + 20 * MB);
    short* xnb = (short*)(ws + 36 * MB);  // [1024,1024] 2MB
    short* Qb  = (short*)(ws + 38 * MB);
    short* Kbb = (short*)(ws + 40 * MB);
    short* VTb = (short*)(ws + 42 * MB);  // 16MB
    short* Scb = (short*)(ws + 58 * MB);  // 16MB -> 74MB

    transpose_k<<<dim3(16, 16), 256, 0, stream>>>(Wq, wqT, 1024, 1024);
    transpose_k<<<dim3(16, 16), 256, 0, stream>>>(Wk, wkT, 1024, 1024);
    transpose_k<<<dim3(128, 16), 256, 0, stream>>>(Wv, wvT, 1024, 8192);

    for (int b = 0; b < 4; b++) {
      const float* xb = x + (long)b * 1048576;
      ln_k<<<1024, 256, 0, stream>>>(xb, g1, b1, xnb);
      gemm128<EPI_BIAS><<<dim3(8, 8, 1), 256, 0, stream>>>(
          xnb, 1024, 0, wqT, 1024, 0, bq, Qb, 0, 1024, nullptr, 1024, 1.0f, 0);
      gemm128<EPI_BIAS><<<dim3(8, 8, 1), 256, 0, stream>>>(
          xnb, 1024, 0, wkT, 1024, 0, bk, Kbb, 0, 1024, nullptr, 1024, 1.0f, 0);
      gemm128<EPI_VT><<<dim3(64, 8, 1), 256, 0, stream>>>(
          xnb, 1024, 0, wvT, 1024, 0, bv, VTb, 0, 0, nullptr, 1024, 1.0f, 0);
      gemm128<EPI_SCALE><<<dim3(8, 8, 8), 256, 0, stream>>>(
          Qb, 1024, 128, Kbb, 1024, 128, nullptr,
          Scb, 1048576, 1024, nullptr, 128, 0.0883883476483184f, 0);
      softmax_k<<<8192, 256, 0, stream>>>(Scb);
      gemm128<EPI_SUM8><<<dim3(8, 8, 8), 256, 0, stream>>>(
          Scb, 1024, 1048576, VTb, 1024, 1048576, nullptr,
          x1, 0, 0, x, 1024, 1.0f, b * 8);
    }
  }

  // ---- FFN phase (overlays attention scratch) ----
  transpose_k<<<dim3(64, 16), 256, 0, stream>>>(W1, w1T, 1024, 4096);
  transpose_k<<<dim3(16, 64), 256, 0, stream>>>(W2, w2T, 4096, 1024);

  ln_k<<<4096, 256, 0, stream>>>(x1, g2, b2, xn2);

  gemm128<EPI_GELU><<<dim3(32, 32, 1), 256, 0, stream>>>(
      xn2, 1024, 0, w1T, 1024, 0, bw1, Hb, 0, 4096, nullptr, 1024, 1.0f, 0);

  gemm128<EPI_FFN2><<<dim3(8, 32, 1), 256, 0, stream>>>(
      Hb, 4096, 0, w2T, 4096, 0, bw2, d_out, 0, 1024, x1, 4096, 1.0f, 0);
}

// Round 5
// 614.038 us; speedup vs baseline: 1.4689x; 1.2696x over previous
//
#include <hip/hip_runtime.h>
#include <hip/hip_bf16.h>
#include <math.h>

// ---------- types ----------
typedef __attribute__((ext_vector_type(8))) short   short8;
typedef __attribute__((ext_vector_type(4))) short   short4v;
typedef __attribute__((ext_vector_type(8))) __bf16  bf16x8;
typedef __attribute__((ext_vector_type(4))) float   f32x4;

typedef const __attribute__((address_space(1))) void cgv_t;
typedef __attribute__((address_space(3))) void lv_t;

__device__ __forceinline__ float bs2f(short s) {
  unsigned int u = ((unsigned int)(unsigned short)s) << 16;
  return __builtin_bit_cast(float, u);
}
__device__ __forceinline__ short f2bs(float f) {
  __hip_bfloat16 h = __float2bfloat16(f);  // RNE
  return __builtin_bit_cast(short, h);
}
// async global->LDS, 16B per lane; lds base must be wave-uniform
__device__ __forceinline__ void glds16(const short* g, short* l) {
  __builtin_amdgcn_global_load_lds((cgv_t*)g, (lv_t*)l, 16, 0, 0);
}

// B=4, S=1024, D=1024, H=8, FF=4096, DK=128. I/O f32; internals bf16.

// ---------- weight transpose + f32->bf16: out[C][R] = bf16(in[R][C]) ----------
__global__ __launch_bounds__(256) void transpose_k(const float* __restrict__ in,
                                                   short* __restrict__ out,
                                                   int R, int C) {
  __shared__ __align__(16) short T[64 * 72];
  const int r0 = blockIdx.y * 64, c0 = blockIdx.x * 64;
  const int t = threadIdx.x;
  {
    const int rr = t >> 4;           // 0..15
    const int cc = (t & 15) << 2;    // 0..60 step 4
#pragma unroll
    for (int h = 0; h < 4; h++) {
      const int row = rr + h * 16;
      f32x4 v = *(const f32x4*)(in + (long)(r0 + row) * C + c0 + cc);
#pragma unroll
      for (int e = 0; e < 4; e++) T[row * 72 + cc + e] = f2bs(v[e]);
    }
  }
  __syncthreads();
  {
    const int cr = t >> 3;           // 0..31
    const int rs = (t & 7) << 3;     // 0..56 step 8
#pragma unroll
    for (int h = 0; h < 2; h++) {
      const int c = cr + h * 32;
      short8 v;
#pragma unroll
      for (int e = 0; e < 8; e++) v[e] = T[(rs + e) * 72 + c];
      *(short8*)(out + (long)(c0 + c) * R + r0 + rs) = v;
    }
  }
}

// ---------- layernorm rows of 1024; f32 in/params; bf16 out ----------
__global__ __launch_bounds__(256) void ln_k(const float* __restrict__ in,
                                            const float* __restrict__ g,
                                            const float* __restrict__ b,
                                            short* __restrict__ out) {
  const int t = threadIdx.x;
  const long base = (long)blockIdx.x * 1024 + t * 4;
  f32x4 f = *(const f32x4*)(in + base);
  float v[4] = {f[0], f[1], f[2], f[3]};
  float s1 = v[0] + v[1] + v[2] + v[3];
  float s2 = v[0]*v[0] + v[1]*v[1] + v[2]*v[2] + v[3]*v[3];
#pragma unroll
  for (int off = 32; off; off >>= 1) {
    s1 += __shfl_xor(s1, off);
    s2 += __shfl_xor(s2, off);
  }
  __shared__ float rs[4], rq[4];
  if ((t & 63) == 0) { rs[t >> 6] = s1; rq[t >> 6] = s2; }
  __syncthreads();
  s1 = rs[0] + rs[1] + rs[2] + rs[3];
  s2 = rq[0] + rq[1] + rq[2] + rq[3];
  const float mean = s1 * (1.0f / 1024.0f);
  const float var  = s2 * (1.0f / 1024.0f) - mean * mean;
  const float rstd = rsqrtf(var + 1e-5f);
  f32x4 gv = *(const f32x4*)(g + t * 4);
  f32x4 bv = *(const f32x4*)(b + t * 4);
  short4v o;
#pragma unroll
  for (int i = 0; i < 4; i++)
    o[i] = f2bs((v[i] - mean) * rstd * gv[i] + bv[i]);
  *(short4v*)(out + base) = o;
}

// ---------- softmax rows of 1024 (bf16 in-place) ----------
__global__ __launch_bounds__(256) void softmax_k(short* __restrict__ sc) {
  const int t = threadIdx.x;
  const long base = (long)blockIdx.x * 1024 + t * 4;
  short4v sv = *(const short4v*)(sc + base);
  float v[4];
#pragma unroll
  for (int i = 0; i < 4; i++) v[i] = bs2f(sv[i]);
  float m = fmaxf(fmaxf(v[0], v[1]), fmaxf(v[2], v[3]));
#pragma unroll
  for (int off = 32; off; off >>= 1) m = fmaxf(m, __shfl_xor(m, off));
  __shared__ float red[4];
  if ((t & 63) == 0) red[t >> 6] = m;
  __syncthreads();
  m = fmaxf(fmaxf(red[0], red[1]), fmaxf(red[2], red[3]));
  float e[4], s = 0.0f;
#pragma unroll
  for (int i = 0; i < 4; i++) { e[i] = expf(v[i] - m); s += e[i]; }
#pragma unroll
  for (int off = 32; off; off >>= 1) s += __shfl_xor(s, off);
  __shared__ float red2[4];
  if ((t & 63) == 0) red2[t >> 6] = s;
  __syncthreads();
  s = red2[0] + red2[1] + red2[2] + red2[3];
  const float inv = 1.0f / s;
  short4v o;
#pragma unroll
  for (int i = 0; i < 4; i++) o[i] = f2bs(e[i] * inv);
  *(short4v*)(sc + base) = o;
}

// ---------- 128xBN MFMA GEMM: C[m][n] = sum_k A[m][k]*Bt[n][k] ----------
// 256 threads = 4 waves (2x2 for BN=128, 4x1 for BN=64); BK=32; glds width-16.
// z offsets: A += (z>>3)*azh + (z&7)*azl; B likewise; C += z*czl (linear);
// bias += (z&7)*biasl.
enum { EPI_BIAS = 0, EPI_SCALE = 1, EPI_VT = 2, EPI_SUM8 = 3, EPI_GELU = 4, EPI_FFN2 = 5 };

template <int EPI, int BN>
__global__ __launch_bounds__(256) void gemm128(
    const short* __restrict__ A, int lda, long azh, long azl,
    const short* __restrict__ Bt, int ldb, long bzh, long bzl,
    const float* __restrict__ bias, long biasl,
    void* __restrict__ outp, long czl, int ldc,
    const void* __restrict__ aux,
    int K, float scale, int zoff) {
  constexpr int WH = (BN == 128) ? 64 : 32;   // rows per wave
  constexpr int RT = WH / 16;                 // row frags per wave
  constexpr int SMEM_SHORTS = (EPI == EPI_VT) ? 17408 : (4096 + BN * 32);
  __shared__ __align__(16) short smem[SMEM_SHORTS];
  short* As = smem;          // [128][32] unpadded (global_load_lds layout)
  short* Bs = smem + 4096;   // [BN][32]

  const int t = threadIdx.x;
  const int wave = t >> 6, lane = t & 63;
  const int llo = lane & 15, lhi = lane >> 4;
  const int wm = (BN == 128) ? (wave >> 1) : wave;
  const int wn = (BN == 128) ? (wave & 1) : 0;
  const int bn0 = blockIdx.x * BN, bm0 = blockIdx.y * 128;
  const int z = blockIdx.z;
  const int zh = z >> 3, zl = z & 7;

  const short* Ab = A + (long)zh * azh + (long)zl * azl;
  const short* Bb = Bt + (long)zh * bzh + (long)zl * bzl;
  bias += (long)zl * biasl;

  f32x4 acc[RT][4];
#pragma unroll
  for (int i = 0; i < RT; i++)
#pragma unroll
    for (int j = 0; j < 4; j++) acc[i][j] = f32x4{0.f, 0.f, 0.f, 0.f};

  // staging: thread t loads 16B at row (t>>2), shorts offset (t&3)*8.
  const int srow = t >> 2, schunk = (t & 3) << 3;
  const short* Ag0 = Ab + (long)(bm0 + srow) * lda + schunk;
  const short* Ag1 = Ab + (long)(bm0 + 64 + srow) * lda + schunk;
  const short* Bg0 = Bb + (long)(bn0 + srow) * ldb + schunk;
  const short* Bg1 = Bb + (long)(bn0 + 64 + srow) * ldb + schunk;
  short* AsW0 = As + (wave * 16) * 32;        // wave-uniform bases
  short* AsW1 = As + (64 + wave * 16) * 32;
  short* BsW0 = Bs + (wave * 16) * 32;
  short* BsW1 = Bs + (64 + wave * 16) * 32;

  const short* aRd = As + (wm * WH + llo) * 32 + lhi * 8;
  const short* bRd = Bs + (wn * 64 + llo) * 32 + lhi * 8;

  for (int kt = 0; kt < K; kt += 32) {
    glds16(Ag0 + kt, AsW0);
    glds16(Ag1 + kt, AsW1);
    glds16(Bg0 + kt, BsW0);
    if (BN == 128) glds16(Bg1 + kt, BsW1);
    __syncthreads();   // drains vmcnt(0): LDS tiles ready
    bf16x8 af[RT], bf[4];
#pragma unroll
    for (int i = 0; i < RT; i++) af[i] = *(const bf16x8*)(aRd + i * 16 * 32);
#pragma unroll
    for (int j = 0; j < 4; j++) bf[j] = *(const bf16x8*)(bRd + j * 16 * 32);
#pragma unroll
    for (int rt = 0; rt < RT; rt++)
#pragma unroll
      for (int ct = 0; ct < 4; ct++)
        acc[rt][ct] = __builtin_amdgcn_mfma_f32_16x16x32_bf16(af[rt], bf[ct], acc[rt][ct], 0, 0, 0);
    __syncthreads();   // protect LDS before next staging round
  }

  if (EPI == EPI_BIAS || EPI == EPI_SCALE || EPI == EPI_GELU) {
    short* C = (short*)outp + (long)z * czl;
#pragma unroll
    for (int ct = 0; ct < 4; ct++) {
      const int col = bn0 + wn * 64 + ct * 16 + llo;
      const float bval = (EPI == EPI_SCALE) ? 0.0f : bias[col];
#pragma unroll
      for (int rt = 0; rt < RT; rt++) {
#pragma unroll
        for (int r = 0; r < 4; r++) {
          const int row = bm0 + wm * WH + rt * 16 + lhi * 4 + r;
          float v = acc[rt][ct][r];
          if (EPI == EPI_SCALE) v *= scale;
          else v += bval;
          if (EPI == EPI_GELU) v = 0.5f * v * (1.0f + erff(v * 0.70710678118654752f));
          C[(long)row * ldc + col] = f2bs(v);
        }
      }
    }
  } else if (EPI == EPI_FFN2) {
    float* C = (float*)outp;
    const float* x1p = (const float*)aux;
#pragma unroll
    for (int ct = 0; ct < 4; ct++) {
      const int col = bn0 + wn * 64 + ct * 16 + llo;
      const float bval = bias[col];
#pragma unroll
      for (int rt = 0; rt < RT; rt++) {
#pragma unroll
        for (int r = 0; r < 4; r++) {
          const int row = bm0 + wm * WH + rt * 16 + lhi * 4 + r;
          C[(long)row * ldc + col] = acc[rt][ct][r] + bval + x1p[(long)row * ldc + col];
        }
      }
    }
  } else if (EPI == EPI_VT) {
    // tile rows = s (batch z), cols = h*1024+d; write VT[(zoff+8z+hh)][d][s]
    short* Ts = smem;  // [col][row], stride 136
#pragma unroll
    for (int ct = 0; ct < 4; ct++) {
      const int c = wn * 64 + ct * 16 + llo;
      const float bval = bias[bn0 + c];
#pragma unroll
      for (int rt = 0; rt < RT; rt++) {
#pragma unroll
        for (int r = 0; r < 4; r++) {
          const int row = wm * WH + rt * 16 + lhi * 4 + r;
          Ts[c * 136 + row] = f2bs(acc[rt][ct][r] + bval);
        }
      }
    }
    __syncthreads();
    const int hh = bn0 >> 10, d0 = bn0 & 1023;
    short* dstbase = (short*)outp + ((long)(zoff + 8 * z + hh) << 20) + (long)d0 * 1024 + bm0;
    const int sc8 = (t & 15) << 3;    // s-chunk (8 shorts)
    const int cb = t >> 4;            // 0..15
#pragma unroll
    for (int j = 0; j < 8; j++) {
      const int c = cb + j * 16;
      *(short8*)(dstbase + (long)c * 1024 + sc8) = *(const short8*)&Ts[c * 136 + sc8];
    }
  } else if (EPI == EPI_SUM8) {
    // attn_flat[g] = sum of 8 consecutive d of ctx row; x1[g]=x[g]+attn[g]
    // LDS bounce -> fully coalesced 64B-line writes.
    float* Ls = (float*)smem;  // [128][16] f32 = 8KB
#pragma unroll
    for (int ct = 0; ct < 4; ct++) {
#pragma unroll
      for (int rt = 0; rt < RT; rt++) {
#pragma unroll
        for (int r = 0; r < 4; r++) {
          float v = acc[rt][ct][r];
          v += __shfl_xor(v, 1);
          v += __shfl_xor(v, 2);
          v += __shfl_xor(v, 4);
          if ((lane & 7) == 0) {
            const int jl = wn * 8 + ct * 2 + ((lane >> 3) & 1);
            const int row = wm * WH + rt * 16 + lhi * 4 + r;
            Ls[row * 16 + jl] = v;
          }
        }
      }
    }
    __syncthreads();
    const float* xg = (const float*)aux;  // FULL x (f32)
    float* x1 = (float*)outp;             // FULL x1
    const int row = t >> 1, jb = (t & 1) << 3;
    const long rfull = (long)(zoff + z) * 1024 + bm0 + row;
    const long g0 = rfull * 128 + (bn0 >> 3) + jb;
    f32x4 a0 = *(const f32x4*)(xg + g0);
    f32x4 a1 = *(const f32x4*)(xg + g0 + 4);
    f32x4 l0 = *(const f32x4*)&Ls[row * 16 + jb];
    f32x4 l1 = *(const f32x4*)&Ls[row * 16 + jb + 4];
    *(f32x4*)(x1 + g0)     = a0 + l0;
    *(f32x4*)(x1 + g0 + 4) = a1 + l1;
  }
}

// ---------- launch ----------
extern "C" void kernel_launch(void* const* d_in, const int* in_sizes, int n_in,
                              void* d_out, int out_size, void* d_ws, size_t ws_size,
                              hipStream_t stream) {
  const float* x   = (const float*)d_in[0];
  // d_in[1] = mask (int32) — unused in infer path
  const float* g1  = (const float*)d_in[2];
  const float* b1  = (const float*)d_in[3];
  const float* Wq  = (const float*)d_in[4];
  const float* bq  = (const float*)d_in[5];
  const float* Wk  = (const float*)d_in[6];
  const float* bk  = (const float*)d_in[7];
  const float* Wv  = (const float*)d_in[8];
  const float* bv  = (const float*)d_in[9];
  const float* g2  = (const float*)d_in[10];
  const float* b2  = (const float*)d_in[11];
  const float* W1  = (const float*)d_in[12];
  const float* bw1 = (const float*)d_in[13];
  const float* W2  = (const float*)d_in[14];
  const float* bw2 = (const float*)d_in[15];

  char* ws = (char*)d_ws;
  const long MB = 1024 * 1024;
  // base layout (all tiers):
  float* bQK = (float*)(ws);             // [2][1024] f32 staged biases (8KB, 1MB slot)
  float* x1  = (float*)(ws + 1 * MB);    // [4096,1024] f32 [1,17)
  short* wqT = (short*)(ws + 17 * MB);   // [17,19)
  short* wkT = (short*)(ws + 19 * MB);   // [19,21) contiguous with wqT
  short* wvT = (short*)(ws + 21 * MB);   // [21,37)
  // FFN overlay (after attention): [17,73)
  short* xn2 = (short*)(ws + 17 * MB);
  short* Hb  = (short*)(ws + 25 * MB);   // [25,57)
  short* w1T = (short*)(ws + 57 * MB);   // [57,65)
  short* w2T = (short*)(ws + 65 * MB);   // [65,73)

  const float SC = 0.0883883476483184f;  // 1/sqrt(128)

  // stage biases for merged Q/K launch
  hipMemcpyAsync(bQK, bq, 4096, hipMemcpyDeviceToDevice, stream);
  hipMemcpyAsync(bQK + 1024, bk, 4096, hipMemcpyDeviceToDevice, stream);

  transpose_k<<<dim3(16, 16), 256, 0, stream>>>(Wq, wqT, 1024, 1024);
  transpose_k<<<dim3(16, 16), 256, 0, stream>>>(Wk, wkT, 1024, 1024);
  transpose_k<<<dim3(128, 16), 256, 0, stream>>>(Wv, wvT, 1024, 8192);

  if (ws_size >= (size_t)(189 * MB)) {
    // ---- T1: fully z-batched attention ----
    short* xn = (short*)(ws + 37 * MB);  // [37,45)
    short* Q  = (short*)(ws + 45 * MB);  // [45,53)
    short* Kb = (short*)(ws + 53 * MB);  // [53,61) contiguous with Q
    short* VT = (short*)(ws + 61 * MB);  // [61,125)
    short* Sc = (short*)(ws + 125 * MB); // [125,189)

    ln_k<<<4096, 256, 0, stream>>>(x, g1, b1, xn);
    // Q and K in one launch: z=0 -> Q, z=1 -> K
    gemm128<EPI_BIAS, 128><<<dim3(8, 32, 2), 256, 0, stream>>>(
        xn, 1024, 0, 0, wqT, 1024, 0, 1048576, bQK, 1024,
        Q, 4194304, 1024, nullptr, 1024, 1.0f, 0);
    // V projection, all batches: z=b
    gemm128<EPI_VT, 128><<<dim3(64, 8, 4), 256, 0, stream>>>(
        xn, 1024, 0, 1048576, wvT, 1024, 0, 0, bv, 0,
        VT, 0, 0, nullptr, 1024, 1.0f, 0);
    // scores, all (b,h): z = b*8+h
    gemm128<EPI_SCALE, 128><<<dim3(8, 8, 32), 256, 0, stream>>>(
        Q, 1024, 1048576, 128, Kb, 1024, 1048576, 128, nullptr, 0,
        Sc, 1048576, 1024, nullptr, 128, SC, 0);
    softmax_k<<<32768, 256, 0, stream>>>(Sc);
    // P@V + sum8 + residual, all (b,h)
    gemm128<EPI_SUM8, 128><<<dim3(8, 8, 32), 256, 0, stream>>>(
        Sc, 1024, 8388608, 1048576, VT, 1024, 8388608, 1048576, nullptr, 0,
        x1, 0, 0, x, 1024, 1.0f, 0);
  } else if (ws_size >= (size_t)(93 * MB)) {
    // ---- T2: full xn/Q/K, per-batch VT/Sc ----
    short* xn  = (short*)(ws + 37 * MB);
    short* Q   = (short*)(ws + 45 * MB);
    short* Kb  = (short*)(ws + 53 * MB);
    short* VTb = (short*)(ws + 61 * MB); // [61,77)
    short* Scb = (short*)(ws + 77 * MB); // [77,93)

    ln_k<<<4096, 256, 0, stream>>>(x, g1, b1, xn);
    gemm128<EPI_BIAS, 128><<<dim3(8, 32, 2), 256, 0, stream>>>(
        xn, 1024, 0, 0, wqT, 1024, 0, 1048576, bQK, 1024,
        Q, 4194304, 1024, nullptr, 1024, 1.0f, 0);
    for (int b = 0; b < 4; b++) {
      gemm128<EPI_VT, 128><<<dim3(64, 8, 1), 256, 0, stream>>>(
          xn + (long)b * 1048576, 1024, 0, 0, wvT, 1024, 0, 0, bv, 0,
          VTb, 0, 0, nullptr, 1024, 1.0f, b * 8);
      gemm128<EPI_SCALE, 128><<<dim3(8, 8, 8), 256, 0, stream>>>(
          Q + (long)b * 1048576, 1024, 0, 128, Kb + (long)b * 1048576, 1024, 0, 128,
          nullptr, 0, Scb, 1048576, 1024, nullptr, 128, SC, 0);
      softmax_k<<<8192, 256, 0, stream>>>(Scb);
      gemm128<EPI_SUM8, 128><<<dim3(8, 8, 8), 256, 0, stream>>>(
          Scb, 1024, 0, 1048576, VTb, 1024, 0, 1048576, nullptr, 0,
          x1, 0, 0, x, 1024, 1.0f, b * 8);
    }
  } else {
    // ---- T3: per-batch everything (75 MB) ----
    short* xnb = (short*)(ws + 37 * MB); // [37,39)
    short* Qb  = (short*)(ws + 39 * MB); // [39,41)
    short* Kbb = (short*)(ws + 41 * MB); // [41,43) contiguous with Qb
    short* VTb = (short*)(ws + 43 * MB); // [43,59)
    short* Scb = (short*)(ws + 59 * MB); // [59,75)

    for (int b = 0; b < 4; b++) {
      const float* xb = x + (long)b * 1048576;
      ln_k<<<1024, 256, 0, stream>>>(xb, g1, b1, xnb);
      gemm128<EPI_BIAS, 128><<<dim3(8, 8, 2), 256, 0, stream>>>(
          xnb, 1024, 0, 0, wqT, 1024, 0, 1048576, bQK, 1024,
          Qb, 1048576, 1024, nullptr, 1024, 1.0f, 0);
      gemm128<EPI_VT, 128><<<dim3(64, 8, 1), 256, 0, stream>>>(
          xnb, 1024, 0, 0, wvT, 1024, 0, 0, bv, 0,
          VTb, 0, 0, nullptr, 1024, 1.0f, b * 8);
      gemm128<EPI_SCALE, 128><<<dim3(8, 8, 8), 256, 0, stream>>>(
          Qb, 1024, 0, 128, Kbb, 1024, 0, 128, nullptr, 0,
          Scb, 1048576, 1024, nullptr, 128, SC, 0);
      softmax_k<<<8192, 256, 0, stream>>>(Scb);
      gemm128<EPI_SUM8, 128><<<dim3(8, 8, 8), 256, 0, stream>>>(
          Scb, 1024, 0, 1048576, VTb, 1024, 0, 1048576, nullptr, 0,
          x1, 0, 0, x, 1024, 1.0f, b * 8);
    }
  }

  // ---- FFN phase (overlays attention scratch) ----
  transpose_k<<<dim3(64, 16), 256, 0, stream>>>(W1, w1T, 1024, 4096);
  transpose_k<<<dim3(16, 64), 256, 0, stream>>>(W2, w2T, 4096, 1024);

  ln_k<<<4096, 256, 0, stream>>>(x1, g2, b2, xn2);

  gemm128<EPI_GELU, 128><<<dim3(32, 32, 1), 256, 0, stream>>>(
      xn2, 1024, 0, 0, w1T, 1024, 0, 0, bw1, 0,
      Hb, 0, 4096, nullptr, 1024, 1.0f, 0);

  gemm128<EPI_FFN2, 64><<<dim3(16, 32, 1), 256, 0, stream>>>(
      Hb, 4096, 0, 0, w2T, 4096, 0, 0, bw2, 0,
      d_out, 0, 1024, x1, 4096, 1.0f, 0);
}

// Round 6
// 459.454 us; speedup vs baseline: 1.9631x; 1.3365x over previous
//
#include <hip/hip_runtime.h>
#include <hip/hip_bf16.h>
#include <math.h>

// ---------- types ----------
typedef __attribute__((ext_vector_type(8))) short   short8;
typedef __attribute__((ext_vector_type(4))) short   short4v;
typedef __attribute__((ext_vector_type(8))) __bf16  bf16x8;
typedef __attribute__((ext_vector_type(4))) float   f32x4;

typedef const __attribute__((address_space(1))) void cgv_t;
typedef __attribute__((address_space(3))) void lv_t;

__device__ __forceinline__ float bs2f(short s) {
  unsigned int u = ((unsigned int)(unsigned short)s) << 16;
  return __builtin_bit_cast(float, u);
}
__device__ __forceinline__ short f2bs(float f) {
  __hip_bfloat16 h = __float2bfloat16(f);  // RNE
  return __builtin_bit_cast(short, h);
}
// async global->LDS, 16B per lane; lds base must be wave-uniform
__device__ __forceinline__ void glds16(const short* g, short* l) {
  __builtin_amdgcn_global_load_lds((cgv_t*)g, (lv_t*)l, 16, 0, 0);
}

// B=4, S=1024, D=1024, H=8, FF=4096, DK=128. I/O f32; internals bf16.
// Head-sum trick: attn[s,g] = sum_k P[s,k] * V8[k,g], V8 = xn @ Wv8,
// Wv8[:,r] = sum_{e<8} Wv[:,8r+e]  (8-col groups of Wv == output groups).

// ---------- weight transpose + f32->bf16: out[C][R] = bf16(in[R][C]) ----------
__global__ __launch_bounds__(256) void transpose_k(const float* __restrict__ in,
                                                   short* __restrict__ out,
                                                   int R, int C) {
  __shared__ __align__(16) short T[64 * 72];
  const int r0 = blockIdx.y * 64, c0 = blockIdx.x * 64;
  const int t = threadIdx.x;
  {
    const int rr = t >> 4;           // 0..15
    const int cc = (t & 15) << 2;    // 0..60 step 4
#pragma unroll
    for (int h = 0; h < 4; h++) {
      const int row = rr + h * 16;
      f32x4 v = *(const f32x4*)(in + (long)(r0 + row) * C + c0 + cc);
#pragma unroll
      for (int e = 0; e < 4; e++) T[row * 72 + cc + e] = f2bs(v[e]);
    }
  }
  __syncthreads();
  {
    const int cr = t >> 3;           // 0..31
    const int rs = (t & 7) << 3;     // 0..56 step 8
#pragma unroll
    for (int h = 0; h < 2; h++) {
      const int c = cr + h * 32;
      short8 v;
#pragma unroll
      for (int e = 0; e < 8; e++) v[e] = T[(rs + e) * 72 + c];
      *(short8*)(out + (long)(c0 + c) * R + r0 + rs) = v;
    }
  }
}

// ---------- wv8T[r][k] = bf16( sum_{e<8} Wv[k][8r+e] ), r,k in [0,1024) ----------
__global__ __launch_bounds__(256) void wv8_k(const float* __restrict__ Wv,
                                             short* __restrict__ out) {
  __shared__ __align__(16) short T[64 * 72];
  const int r0 = blockIdx.x * 64, k0 = blockIdx.y * 64;
  const int t = threadIdx.x;
  const int wave = t >> 6, lane = t & 63;
  const int r = r0 + lane;
#pragma unroll 4
  for (int i = 0; i < 16; i++) {
    const int k = k0 + wave * 16 + i;
    const float* src = Wv + (long)k * 8192 + 8 * r;
    f32x4 a = *(const f32x4*)src;
    f32x4 b = *(const f32x4*)(src + 4);
    float s = (a[0] + a[1] + a[2] + a[3]) + (b[0] + b[1] + b[2] + b[3]);
    T[lane * 72 + wave * 16 + i] = f2bs(s);
  }
  __syncthreads();
  const int rr = t >> 3, kc = (t & 7) << 3;
#pragma unroll
  for (int half = 0; half < 2; half++) {
    const int rl = rr + half * 32;
    *(short8*)(out + (long)(r0 + rl) * 1024 + k0 + kc) = *(const short8*)&T[rl * 72 + kc];
  }
}

// ---------- bv8[r] = sum_{e<8} bv[8r+e] ----------
__global__ __launch_bounds__(256) void bv8_k(const float* __restrict__ bv,
                                             float* __restrict__ out) {
  const int r = blockIdx.x * 256 + threadIdx.x;
  f32x4 a = *(const f32x4*)(bv + 8 * r);
  f32x4 b = *(const f32x4*)(bv + 8 * r + 4);
  out[r] = (a[0] + a[1] + a[2] + a[3]) + (b[0] + b[1] + b[2] + b[3]);
}

// ---------- layernorm rows of 1024; f32 in/params; bf16 out ----------
__global__ __launch_bounds__(256) void ln_k(const float* __restrict__ in,
                                            const float* __restrict__ g,
                                            const float* __restrict__ b,
                                            short* __restrict__ out) {
  const int t = threadIdx.x;
  const long base = (long)blockIdx.x * 1024 + t * 4;
  f32x4 f = *(const f32x4*)(in + base);
  float v[4] = {f[0], f[1], f[2], f[3]};
  float s1 = v[0] + v[1] + v[2] + v[3];
  float s2 = v[0]*v[0] + v[1]*v[1] + v[2]*v[2] + v[3]*v[3];
#pragma unroll
  for (int off = 32; off; off >>= 1) {
    s1 += __shfl_xor(s1, off);
    s2 += __shfl_xor(s2, off);
  }
  __shared__ float rs[4], rq[4];
  if ((t & 63) == 0) { rs[t >> 6] = s1; rq[t >> 6] = s2; }
  __syncthreads();
  s1 = rs[0] + rs[1] + rs[2] + rs[3];
  s2 = rq[0] + rq[1] + rq[2] + rq[3];
  const float mean = s1 * (1.0f / 1024.0f);
  const float var  = s2 * (1.0f / 1024.0f) - mean * mean;
  const float rstd = rsqrtf(var + 1e-5f);
  f32x4 gv = *(const f32x4*)(g + t * 4);
  f32x4 bv = *(const f32x4*)(b + t * 4);
  short4v o;
#pragma unroll
  for (int i = 0; i < 4; i++)
    o[i] = f2bs((v[i] - mean) * rstd * gv[i] + bv[i]);
  *(short4v*)(out + base) = o;
}

// ---------- softmax rows of 1024 (bf16 in-place) ----------
__global__ __launch_bounds__(256) void softmax_k(short* __restrict__ sc) {
  const int t = threadIdx.x;
  const long base = (long)blockIdx.x * 1024 + t * 4;
  short4v sv = *(const short4v*)(sc + base);
  float v[4];
#pragma unroll
  for (int i = 0; i < 4; i++) v[i] = bs2f(sv[i]);
  float m = fmaxf(fmaxf(v[0], v[1]), fmaxf(v[2], v[3]));
#pragma unroll
  for (int off = 32; off; off >>= 1) m = fmaxf(m, __shfl_xor(m, off));
  __shared__ float red[4];
  if ((t & 63) == 0) red[t >> 6] = m;
  __syncthreads();
  m = fmaxf(fmaxf(red[0], red[1]), fmaxf(red[2], red[3]));
  float e[4], s = 0.0f;
#pragma unroll
  for (int i = 0; i < 4; i++) { e[i] = expf(v[i] - m); s += e[i]; }
#pragma unroll
  for (int off = 32; off; off >>= 1) s += __shfl_xor(s, off);
  __shared__ float red2[4];
  if ((t & 63) == 0) red2[t >> 6] = s;
  __syncthreads();
  s = red2[0] + red2[1] + red2[2] + red2[3];
  const float inv = 1.0f / s;
  short4v o;
#pragma unroll
  for (int i = 0; i < 4; i++) o[i] = f2bs(e[i] * inv);
  *(short4v*)(sc + base) = o;
}

// ---------- 128xBN MFMA GEMM: C[m][n] = sum_k A[m][k]*Bt[n][k] ----------
// 256 threads = 4 waves (2x2 for BN=128, 4x1 for BN=64); BK=32; glds width-16.
// z offsets: A += (z>>3)*azh + (z&7)*azl; B likewise; bias += (z&7)*biasl.
enum { EPI_SCALE = 1, EPI_GELU = 4, EPI_FFN2 = 5, EPI_QKV8 = 6, EPI_PV8 = 7 };

template <int EPI, int BN>
__global__ __launch_bounds__(256) void gemm128(
    const short* __restrict__ A, int lda, long azh, long azl,
    const short* __restrict__ Bt, int ldb, long bzh, long bzl,
    const float* __restrict__ bias, long biasl,
    void* __restrict__ outp, long czl, int ldc,
    const void* __restrict__ aux,
    int K, float scale) {
  constexpr int WH = (BN == 128) ? 64 : 32;   // rows per wave
  constexpr int RT = WH / 16;                 // row frags per wave
  constexpr int SMEM_SHORTS = (EPI == EPI_QKV8) ? 17408 : (4096 + BN * 32);
  __shared__ __align__(16) short smem[SMEM_SHORTS];
  short* As = smem;          // [128][32] unpadded (global_load_lds layout)
  short* Bs = smem + 4096;   // [BN][32]

  const int t = threadIdx.x;
  const int wave = t >> 6, lane = t & 63;
  const int llo = lane & 15, lhi = lane >> 4;
  const int wm = (BN == 128) ? (wave >> 1) : wave;
  const int wn = (BN == 128) ? (wave & 1) : 0;
  const int bn0 = blockIdx.x * BN, bm0 = blockIdx.y * 128;
  const int z = blockIdx.z;
  const int zh = z >> 3, zl = z & 7;

  const short* Ab = A + (long)zh * azh + (long)zl * azl;
  const short* Bb = Bt + (long)zh * bzh + (long)zl * bzl;
  bias += (long)zl * biasl;

  f32x4 acc[RT][4];
#pragma unroll
  for (int i = 0; i < RT; i++)
#pragma unroll
    for (int j = 0; j < 4; j++) acc[i][j] = f32x4{0.f, 0.f, 0.f, 0.f};

  // staging: thread t loads 16B at row (t>>2), shorts offset (t&3)*8.
  const int srow = t >> 2, schunk = (t & 3) << 3;
  const short* Ag0 = Ab + (long)(bm0 + srow) * lda + schunk;
  const short* Ag1 = Ab + (long)(bm0 + 64 + srow) * lda + schunk;
  const short* Bg0 = Bb + (long)(bn0 + srow) * ldb + schunk;
  const short* Bg1 = Bb + (long)(bn0 + 64 + srow) * ldb + schunk;
  short* AsW0 = As + (wave * 16) * 32;        // wave-uniform bases
  short* AsW1 = As + (64 + wave * 16) * 32;
  short* BsW0 = Bs + (wave * 16) * 32;
  short* BsW1 = Bs + (64 + wave * 16) * 32;

  const short* aRd = As + (wm * WH + llo) * 32 + lhi * 8;
  const short* bRd = Bs + (wn * 64 + llo) * 32 + lhi * 8;

  for (int kt = 0; kt < K; kt += 32) {
    glds16(Ag0 + kt, AsW0);
    glds16(Ag1 + kt, AsW1);
    glds16(Bg0 + kt, BsW0);
    if (BN == 128) glds16(Bg1 + kt, BsW1);
    __syncthreads();   // drains vmcnt(0): LDS tiles ready
    bf16x8 af[RT], bf[4];
#pragma unroll
    for (int i = 0; i < RT; i++) af[i] = *(const bf16x8*)(aRd + i * 16 * 32);
#pragma unroll
    for (int j = 0; j < 4; j++) bf[j] = *(const bf16x8*)(bRd + j * 16 * 32);
#pragma unroll
    for (int rt = 0; rt < RT; rt++)
#pragma unroll
      for (int ct = 0; ct < 4; ct++)
        acc[rt][ct] = __builtin_amdgcn_mfma_f32_16x16x32_bf16(af[rt], bf[ct], acc[rt][ct], 0, 0, 0);
    __syncthreads();   // protect LDS before next staging round
  }

  if (EPI == EPI_SCALE || EPI == EPI_GELU || (EPI == EPI_QKV8 && blockIdx.z < 2)) {
    short* C = (short*)outp + (long)z * czl;
#pragma unroll
    for (int ct = 0; ct < 4; ct++) {
      const int col = bn0 + wn * 64 + ct * 16 + llo;
      const float bval = (EPI == EPI_SCALE) ? 0.0f : bias[col];
#pragma unroll
      for (int rt = 0; rt < RT; rt++) {
#pragma unroll
        for (int r = 0; r < 4; r++) {
          const int row = bm0 + wm * WH + rt * 16 + lhi * 4 + r;
          float v = acc[rt][ct][r];
          if (EPI == EPI_SCALE) v *= scale;
          else v += bval;
          if (EPI == EPI_GELU) v = 0.5f * v * (1.0f + erff(v * 0.70710678118654752f));
          C[(long)row * ldc + col] = f2bs(v);
        }
      }
    }
  } else if (EPI == EPI_QKV8) {
    // z==2: V8 projection; write transposed V8T[(b*8+head)][g][s] via LDS.
    short* Ts = smem;  // [col][row], stride 136
#pragma unroll
    for (int ct = 0; ct < 4; ct++) {
      const int c = wn * 64 + ct * 16 + llo;
      const float bval = bias[bn0 + c];
#pragma unroll
      for (int rt = 0; rt < RT; rt++) {
#pragma unroll
        for (int r = 0; r < 4; r++) {
          const int row = wm * WH + rt * 16 + lhi * 4 + r;
          Ts[c * 136 + row] = f2bs(acc[rt][ct][r] + bval);
        }
      }
    }
    __syncthreads();
    const int bb = bm0 >> 10, s0 = bm0 & 1023, head = bn0 >> 7;
    short* dstbase = (short*)aux + ((long)(bb * 8 + head)) * 131072 + s0;
    const int sc8 = (t & 15) << 3;    // s-chunk (8 shorts)
    const int cb = t >> 4;            // 0..15
#pragma unroll
    for (int j = 0; j < 8; j++) {
      const int c = cb + j * 16;      // g index 0..127
      *(short8*)(dstbase + (long)c * 1024 + sc8) = *(const short8*)&Ts[c * 136 + sc8];
    }
  } else if (EPI == EPI_FFN2) {
    float* C = (float*)outp;
    const float* x1p = (const float*)aux;
#pragma unroll
    for (int ct = 0; ct < 4; ct++) {
      const int col = bn0 + wn * 64 + ct * 16 + llo;
      const float bval = bias[col];
#pragma unroll
      for (int rt = 0; rt < RT; rt++) {
#pragma unroll
        for (int r = 0; r < 4; r++) {
          const int row = bm0 + wm * WH + rt * 16 + lhi * 4 + r;
          C[(long)row * ldc + col] = acc[rt][ct][r] + bval + x1p[(long)row * ldc + col];
        }
      }
    }
  } else if (EPI == EPI_PV8) {
    // out cols ARE attn groups: x1[(z*1024+row)*128+col] = x[..] + acc
    const float* xg = (const float*)aux;
    float* x1 = (float*)outp;
#pragma unroll
    for (int ct = 0; ct < 4; ct++) {
      const int col = wn * 64 + ct * 16 + llo;   // bn0 == 0
#pragma unroll
      for (int rt = 0; rt < RT; rt++) {
#pragma unroll
        for (int r = 0; r < 4; r++) {
          const int row = bm0 + wm * WH + rt * 16 + lhi * 4 + r;
          const long g = ((long)z * 1024 + row) * 128 + col;
          x1[g] = xg[g] + acc[rt][ct][r];
        }
      }
    }
  }
}

// ---------- launch ----------
extern "C" void kernel_launch(void* const* d_in, const int* in_sizes, int n_in,
                              void* d_out, int out_size, void* d_ws, size_t ws_size,
                              hipStream_t stream) {
  const float* x   = (const float*)d_in[0];
  // d_in[1] = mask (int32) — unused in infer path
  const float* g1  = (const float*)d_in[2];
  const float* b1  = (const float*)d_in[3];
  const float* Wq  = (const float*)d_in[4];
  const float* bq  = (const float*)d_in[5];
  const float* Wk  = (const float*)d_in[6];
  const float* bk  = (const float*)d_in[7];
  const float* Wv  = (const float*)d_in[8];
  const float* bv  = (const float*)d_in[9];
  const float* g2  = (const float*)d_in[10];
  const float* b2  = (const float*)d_in[11];
  const float* W1  = (const float*)d_in[12];
  const float* bw1 = (const float*)d_in[13];
  const float* W2  = (const float*)d_in[14];
  const float* bw2 = (const float*)d_in[15];

  char* ws = (char*)d_ws;
  const long MB = 1024 * 1024;
  // layout (peak 119MB; ws proven >= 189MB in earlier rounds):
  float* bQKV = (float*)(ws);            // [3][1024] f32: bq | bk | bv8
  float* x1   = (float*)(ws + 1 * MB);   // [4096,1024] f32  [1,17)
  short* wqT  = (short*)(ws + 17 * MB);  // [17,19)
  short* wkT  = (short*)(ws + 19 * MB);  // [19,21)  contiguous with wqT
  short* wv8T = (short*)(ws + 21 * MB);  // [21,23)  contiguous (z*1MB shorts)
  short* xn   = (short*)(ws + 23 * MB);  // [23,31)
  short* Q    = (short*)(ws + 31 * MB);  // [31,39)
  short* Kb   = (short*)(ws + 39 * MB);  // [39,47)  contiguous with Q
  short* V8T  = (short*)(ws + 47 * MB);  // [32][128][1024] bf16 [47,55)
  short* Sc   = (short*)(ws + 55 * MB);  // [32][1024][1024] bf16 [55,119)
  // FFN overlay (attention scratch dead by then):
  short* xn2  = (short*)(ws + 17 * MB);  // [17,25)
  short* Hb   = (short*)(ws + 25 * MB);  // [25,57)
  short* w1T  = (short*)(ws + 57 * MB);  // [57,65)
  short* w2T  = (short*)(ws + 65 * MB);  // [65,73)

  const float SC = 0.0883883476483184f;  // 1/sqrt(128)

  // stage biases: [bq; bk; bv8]
  hipMemcpyAsync(bQKV, bq, 4096, hipMemcpyDeviceToDevice, stream);
  hipMemcpyAsync(bQKV + 1024, bk, 4096, hipMemcpyDeviceToDevice, stream);
  bv8_k<<<4, 256, 0, stream>>>(bv, bQKV + 2048);

  transpose_k<<<dim3(16, 16), 256, 0, stream>>>(Wq, wqT, 1024, 1024);
  transpose_k<<<dim3(16, 16), 256, 0, stream>>>(Wk, wkT, 1024, 1024);
  wv8_k<<<dim3(16, 16), 256, 0, stream>>>(Wv, wv8T);

  ln_k<<<4096, 256, 0, stream>>>(x, g1, b1, xn);

  // Q (z=0), K (z=1) -> Q/Kb; V8 (z=2) -> V8T transposed
  gemm128<EPI_QKV8, 128><<<dim3(8, 32, 3), 256, 0, stream>>>(
      xn, 1024, 0, 0, wqT, 1024, 0, 1048576, bQKV, 1024,
      Q, 4194304, 1024, V8T, 1024, 1.0f);

  // scores = Q K^T / sqrt(128), z = b*8+h
  gemm128<EPI_SCALE, 128><<<dim3(8, 8, 32), 256, 0, stream>>>(
      Q, 1024, 1048576, 128, Kb, 1024, 1048576, 128, nullptr, 0,
      Sc, 1048576, 1024, nullptr, 128, SC);

  softmax_k<<<32768, 256, 0, stream>>>(Sc);

  // attn+residual: P @ V8T -> x1 (f32), z = b*8+h
  gemm128<EPI_PV8, 128><<<dim3(1, 8, 32), 256, 0, stream>>>(
      Sc, 1024, 8388608, 1048576, V8T, 1024, 1048576, 131072, nullptr, 0,
      x1, 0, 0, x, 1024, 1.0f);

  // ---- FFN phase ----
  transpose_k<<<dim3(64, 16), 256, 0, stream>>>(W1, w1T, 1024, 4096);
  transpose_k<<<dim3(16, 64), 256, 0, stream>>>(W2, w2T, 4096, 1024);

  ln_k<<<4096, 256, 0, stream>>>(x1, g2, b2, xn2);

  gemm128<EPI_GELU, 128><<<dim3(32, 32, 1), 256, 0, stream>>>(
      xn2, 1024, 0, 0, w1T, 1024, 0, 0, bw1, 0,
      Hb, 0, 4096, nullptr, 1024, 1.0f);

  gemm128<EPI_FFN2, 64><<<dim3(16, 32, 1), 256, 0, stream>>>(
      Hb, 4096, 0, 0, w2T, 4096, 0, 0, bw2, 0,
      d_out, 0, 1024, x1, 4096, 1.0f);
}

// Round 8
// 419.146 us; speedup vs baseline: 2.1518x; 1.0962x over previous
//
#include <hip/hip_runtime.h>
#include <hip/hip_bf16.h>
#include <math.h>

// ---------- types ----------
typedef __attribute__((ext_vector_type(8))) short   short8;
typedef __attribute__((ext_vector_type(4))) short   short4v;
typedef __attribute__((ext_vector_type(8))) __bf16  bf16x8;
typedef __attribute__((ext_vector_type(4))) float   f32x4;

typedef const __attribute__((address_space(1))) void cgv_t;
typedef __attribute__((address_space(3))) void lv_t;

__device__ __forceinline__ float bs2f(short s) {
  unsigned int u = ((unsigned int)(unsigned short)s) << 16;
  return __builtin_bit_cast(float, u);
}
__device__ __forceinline__ short f2bs(float f) {
  __hip_bfloat16 h = __float2bfloat16(f);  // RNE
  return __builtin_bit_cast(short, h);
}
// async global->LDS, 16B per lane; lds base must be wave-uniform
__device__ __forceinline__ void glds16(const short* g, short* l) {
  __builtin_amdgcn_global_load_lds((cgv_t*)g, (lv_t*)l, 16, 0, 0);
}

// B=4, S=1024, D=1024, H=8, FF=4096, DK=128. I/O f32; internals bf16.
// Head-sum trick: attn[s,g] = sum_k P[s,k] * V8[k,g], V8 = xn @ Wv8,
// Wv8[:,r] = sum_{e<8} Wv[:,8r+e]. Attention fused flash-style.
// IMPORTANT: reference's raw reshape means the (b,h,s,gg) attention value
// lands at x1 FLAT index ((b*8+h)*1024+s)*128+gg (verified by round 6).

// ---------- weight transpose + f32->bf16: out[C][R] = bf16(in[R][C]) ----------
__global__ __launch_bounds__(256) void transpose_k(const float* __restrict__ in,
                                                   short* __restrict__ out,
                                                   int R, int C) {
  __shared__ __align__(16) short T[64 * 72];
  const int r0 = blockIdx.y * 64, c0 = blockIdx.x * 64;
  const int t = threadIdx.x;
  {
    const int rr = t >> 4;           // 0..15
    const int cc = (t & 15) << 2;    // 0..60 step 4
#pragma unroll
    for (int h = 0; h < 4; h++) {
      const int row = rr + h * 16;
      f32x4 v = *(const f32x4*)(in + (long)(r0 + row) * C + c0 + cc);
#pragma unroll
      for (int e = 0; e < 4; e++) T[row * 72 + cc + e] = f2bs(v[e]);
    }
  }
  __syncthreads();
  {
    const int cr = t >> 3;           // 0..31
    const int rs = (t & 7) << 3;     // 0..56 step 8
#pragma unroll
    for (int h = 0; h < 2; h++) {
      const int c = cr + h * 32;
      short8 v;
#pragma unroll
      for (int e = 0; e < 8; e++) v[e] = T[(rs + e) * 72 + c];
      *(short8*)(out + (long)(c0 + c) * R + r0 + rs) = v;
    }
  }
}

// ---------- wv8T[r][k] = bf16( sum_{e<8} Wv[k][8r+e] ) ----------
__global__ __launch_bounds__(256) void wv8_k(const float* __restrict__ Wv,
                                             short* __restrict__ out) {
  __shared__ __align__(16) short T[64 * 72];
  const int r0 = blockIdx.x * 64, k0 = blockIdx.y * 64;
  const int t = threadIdx.x;
  const int wave = t >> 6, lane = t & 63;
  const int r = r0 + lane;
#pragma unroll 4
  for (int i = 0; i < 16; i++) {
    const int k = k0 + wave * 16 + i;
    const float* src = Wv + (long)k * 8192 + 8 * r;
    f32x4 a = *(const f32x4*)src;
    f32x4 b = *(const f32x4*)(src + 4);
    float s = (a[0] + a[1] + a[2] + a[3]) + (b[0] + b[1] + b[2] + b[3]);
    T[lane * 72 + wave * 16 + i] = f2bs(s);
  }
  __syncthreads();
  const int rr = t >> 3, kc = (t & 7) << 3;
#pragma unroll
  for (int half = 0; half < 2; half++) {
    const int rl = rr + half * 32;
    *(short8*)(out + (long)(r0 + rl) * 1024 + k0 + kc) = *(const short8*)&T[rl * 72 + kc];
  }
}

// ---------- bv8[r] = sum_{e<8} bv[8r+e] ----------
__global__ __launch_bounds__(256) void bv8_k(const float* __restrict__ bv,
                                             float* __restrict__ out) {
  const int r = blockIdx.x * 256 + threadIdx.x;
  f32x4 a = *(const f32x4*)(bv + 8 * r);
  f32x4 b = *(const f32x4*)(bv + 8 * r + 4);
  out[r] = (a[0] + a[1] + a[2] + a[3]) + (b[0] + b[1] + b[2] + b[3]);
}

// ---------- layernorm rows of 1024; f32 in/params; bf16 out ----------
__global__ __launch_bounds__(256) void ln_k(const float* __restrict__ in,
                                            const float* __restrict__ g,
                                            const float* __restrict__ b,
                                            short* __restrict__ out) {
  const int t = threadIdx.x;
  const long base = (long)blockIdx.x * 1024 + t * 4;
  f32x4 f = *(const f32x4*)(in + base);
  float v[4] = {f[0], f[1], f[2], f[3]};
  float s1 = v[0] + v[1] + v[2] + v[3];
  float s2 = v[0]*v[0] + v[1]*v[1] + v[2]*v[2] + v[3]*v[3];
#pragma unroll
  for (int off = 32; off; off >>= 1) {
    s1 += __shfl_xor(s1, off);
    s2 += __shfl_xor(s2, off);
  }
  __shared__ float rs[4], rq[4];
  if ((t & 63) == 0) { rs[t >> 6] = s1; rq[t >> 6] = s2; }
  __syncthreads();
  s1 = rs[0] + rs[1] + rs[2] + rs[3];
  s2 = rq[0] + rq[1] + rq[2] + rq[3];
  const float mean = s1 * (1.0f / 1024.0f);
  const float var  = s2 * (1.0f / 1024.0f) - mean * mean;
  const float rstd = rsqrtf(var + 1e-5f);
  f32x4 gv = *(const f32x4*)(g + t * 4);
  f32x4 bv = *(const f32x4*)(b + t * 4);
  short4v o;
#pragma unroll
  for (int i = 0; i < 4; i++)
    o[i] = f2bs((v[i] - mean) * rstd * gv[i] + bv[i]);
  *(short4v*)(out + base) = o;
}

// ---------- fused flash attention (+head-sum + residual) ----------
// grid (16, 32): x = q-tile (64 rows), y = bh. block 256 = 4 waves, each wave
// owns a 16-row band (row stats fully within-wave). LDS: Q 16K + K/P 32K +
// V 32K = 80KB -> 2 blocks/CU. All tiles: 4 slabs of [rows][32] shorts.
__global__ __launch_bounds__(256, 2) void flash_k(
    const short* __restrict__ Qg_, const short* __restrict__ Kg_,
    const short* __restrict__ V8T, const float* __restrict__ xg,
    float* __restrict__ x1) {
  __shared__ __align__(16) short smem[40960];  // 80 KB exactly
  short* Qs = smem;            // 4 * [64][32]  (slab 2048 shorts)
  short* Ks = smem + 8192;     // 4 * [128][32] (slab 4096); P reuses rows 0..63
  short* Vs = smem + 24576;    // 4 * [128][32]

  const int t = threadIdx.x;
  const int wave = t >> 6, lane = t & 63;
  const int llo = lane & 15, lhi = lane >> 4;
  const int q0 = blockIdx.x * 64;
  const int bh = blockIdx.y, b = bh >> 3, h = bh & 7;
  const float SC = 0.0883883476483184f;  // 1/sqrt(128)

  const short* Qg = Qg_ + ((long)(b * 1024 + q0)) * 1024 + h * 128;
  const short* Kg = Kg_ + ((long)b * 1024) * 1024 + h * 128;
  const short* Vg = V8T + (long)bh * 131072;   // [128 g][1024 s]

  const int srow = t >> 2, schunk = (t & 3) << 3;
  const int wbase = wave * 512;          // wave-uniform stage base (shorts)
  const int arow = (wave * 16 + llo) * 32 + lhi * 8;

  // stage Q once (4 slabs x 64 rows)
#pragma unroll
  for (int kk = 0; kk < 4; kk++)
    glds16(Qg + (long)srow * 1024 + kk * 32 + schunk, Qs + kk * 2048 + wbase);

  f32x4 o[8];
  float mR[4], lR[4];
#pragma unroll
  for (int i = 0; i < 8; i++) o[i] = f32x4{0.f, 0.f, 0.f, 0.f};
#pragma unroll
  for (int r = 0; r < 4; r++) { mR[r] = -1e30f; lR[r] = 0.f; }

  for (int it = 0; it < 8; it++) {
    const int kt0 = it * 128;
    // stage K-tile [128 n][128 d] and V-tile [128 g][128 s]
#pragma unroll
    for (int kk = 0; kk < 4; kk++) {
      glds16(Kg + (long)(kt0 + srow) * 1024 + kk * 32 + schunk,
             Ks + kk * 4096 + wbase);
      glds16(Kg + (long)(kt0 + 64 + srow) * 1024 + kk * 32 + schunk,
             Ks + kk * 4096 + 2048 + wbase);
      glds16(Vg + (long)srow * 1024 + kt0 + kk * 32 + schunk,
             Vs + kk * 4096 + wbase);
      glds16(Vg + (long)(64 + srow) * 1024 + kt0 + kk * 32 + schunk,
             Vs + kk * 4096 + 2048 + wbase);
    }
    __syncthreads();   // drain glds: K,V (and Q on it=0) resident

    // S = Q K^T : wave rows [wave*16,+16), cols 0..127
    f32x4 s[8];
#pragma unroll
    for (int i = 0; i < 8; i++) s[i] = f32x4{0.f, 0.f, 0.f, 0.f};
#pragma unroll
    for (int kk = 0; kk < 4; kk++) {
      bf16x8 aq = *(const bf16x8*)(Qs + kk * 2048 + arow);
#pragma unroll
      for (int ct = 0; ct < 8; ct++) {
        bf16x8 bk = *(const bf16x8*)(Ks + kk * 4096 + (ct * 16 + llo) * 32 + lhi * 8);
        s[ct] = __builtin_amdgcn_mfma_f32_16x16x32_bf16(aq, bk, s[ct], 0, 0, 0);
      }
    }
    // online softmax, rows = lhi*4+r within this wave's band
#pragma unroll
    for (int ct = 0; ct < 8; ct++)
#pragma unroll
      for (int r = 0; r < 4; r++) s[ct][r] *= SC;
    float alpha[4];
#pragma unroll
    for (int r = 0; r < 4; r++) {
      float mt = s[0][r];
#pragma unroll
      for (int ct = 1; ct < 8; ct++) mt = fmaxf(mt, s[ct][r]);
      mt = fmaxf(mt, __shfl_xor(mt, 1));
      mt = fmaxf(mt, __shfl_xor(mt, 2));
      mt = fmaxf(mt, __shfl_xor(mt, 4));
      mt = fmaxf(mt, __shfl_xor(mt, 8));
      const float mn = fmaxf(mR[r], mt);
      alpha[r] = expf(mR[r] - mn);
      mR[r] = mn;
    }
#pragma unroll
    for (int ct = 0; ct < 8; ct++)
#pragma unroll
      for (int r = 0; r < 4; r++) s[ct][r] = expf(s[ct][r] - mR[r]);
#pragma unroll
    for (int ct = 0; ct < 8; ct++)
#pragma unroll
      for (int r = 0; r < 4; r++) o[ct][r] *= alpha[r];
#pragma unroll
    for (int r = 0; r < 4; r++) {
      float ls = s[0][r];
#pragma unroll
      for (int ct = 1; ct < 8; ct++) ls += s[ct][r];
      ls += __shfl_xor(ls, 1);
      ls += __shfl_xor(ls, 2);
      ls += __shfl_xor(ls, 4);
      ls += __shfl_xor(ls, 8);
      lR[r] = lR[r] * alpha[r] + ls;
    }
    __syncthreads();   // all waves done reading Ks -> safe to overwrite with P

    // write P (bf16) into Ks rows 0..63: P[m][k] at slab(k>>5)+m*32+(k&31)
#pragma unroll
    for (int ct = 0; ct < 8; ct++) {
      const int base = (ct >> 1) * 4096 + ((ct & 1) << 4) + llo;
#pragma unroll
      for (int r = 0; r < 4; r++)
        Ks[base + (wave * 16 + lhi * 4 + r) * 32] = f2bs(s[ct][r]);
    }
    __syncthreads();   // P visible

    // O += P V8 : cols g = 0..127
#pragma unroll
    for (int kk = 0; kk < 4; kk++) {
      bf16x8 ap = *(const bf16x8*)(Ks + kk * 4096 + arow);
#pragma unroll
      for (int ct = 0; ct < 8; ct++) {
        bf16x8 bv = *(const bf16x8*)(Vs + kk * 4096 + (ct * 16 + llo) * 32 + lhi * 8);
        o[ct] = __builtin_amdgcn_mfma_f32_16x16x32_bf16(ap, bv, o[ct], 0, 0, 0);
      }
    }
    __syncthreads();   // protect LDS before next stage
  }

  // epilogue: x1 = x + O/l at the RESHAPE-SCATTER index:
  // flat = ((b*8+h)*1024 + s)*128 + gg   (raw reshape semantics)
  float inv[4];
#pragma unroll
  for (int r = 0; r < 4; r++) inv[r] = 1.0f / lR[r];
#pragma unroll
  for (int ct = 0; ct < 8; ct++) {
#pragma unroll
    for (int r = 0; r < 4; r++) {
      const int row = q0 + wave * 16 + lhi * 4 + r;
      const long idx = ((long)(b * 8 + h) * 1024 + row) * 128 + ct * 16 + llo;
      x1[idx] = xg[idx] + o[ct][r] * inv[r];
    }
  }
}

// ---------- 128xBN MFMA GEMM: C[m][n] = sum_k A[m][k]*Bt[n][k] ----------
enum { EPI_SCALE = 1, EPI_GELU = 4, EPI_FFN2 = 5, EPI_QKV8 = 6 };

template <int EPI, int BN>
__global__ __launch_bounds__(256) void gemm128(
    const short* __restrict__ A, int lda, long azh, long azl,
    const short* __restrict__ Bt, int ldb, long bzh, long bzl,
    const float* __restrict__ bias, long biasl,
    void* __restrict__ outp, long czl, int ldc,
    const void* __restrict__ aux,
    int K, float scale) {
  constexpr int WH = (BN == 128) ? 64 : 32;   // rows per wave
  constexpr int RT = WH / 16;                 // row frags per wave
  constexpr int SMEM_SHORTS = (EPI == EPI_QKV8) ? 17408 : (4096 + BN * 32);
  __shared__ __align__(16) short smem[SMEM_SHORTS];
  short* As = smem;          // [128][32] unpadded (global_load_lds layout)
  short* Bs = smem + 4096;   // [BN][32]

  const int t = threadIdx.x;
  const int wave = t >> 6, lane = t & 63;
  const int llo = lane & 15, lhi = lane >> 4;
  const int wm = (BN == 128) ? (wave >> 1) : wave;
  const int wn = (BN == 128) ? (wave & 1) : 0;
  const int bn0 = blockIdx.x * BN, bm0 = blockIdx.y * 128;
  const int z = blockIdx.z;
  const int zh = z >> 3, zl = z & 7;

  const short* Ab = A + (long)zh * azh + (long)zl * azl;
  const short* Bb = Bt + (long)zh * bzh + (long)zl * bzl;
  bias += (long)zl * biasl;

  f32x4 acc[RT][4];
#pragma unroll
  for (int i = 0; i < RT; i++)
#pragma unroll
    for (int j = 0; j < 4; j++) acc[i][j] = f32x4{0.f, 0.f, 0.f, 0.f};

  const int srow = t >> 2, schunk = (t & 3) << 3;
  const short* Ag0 = Ab + (long)(bm0 + srow) * lda + schunk;
  const short* Ag1 = Ab + (long)(bm0 + 64 + srow) * lda + schunk;
  const short* Bg0 = Bb + (long)(bn0 + srow) * ldb + schunk;
  const short* Bg1 = Bb + (long)(bn0 + 64 + srow) * ldb + schunk;
  short* AsW0 = As + (wave * 16) * 32;        // wave-uniform bases
  short* AsW1 = As + (64 + wave * 16) * 32;
  short* BsW0 = Bs + (wave * 16) * 32;
  short* BsW1 = Bs + (64 + wave * 16) * 32;

  const short* aRd = As + (wm * WH + llo) * 32 + lhi * 8;
  const short* bRd = Bs + (wn * 64 + llo) * 32 + lhi * 8;

  for (int kt = 0; kt < K; kt += 32) {
    glds16(Ag0 + kt, AsW0);
    glds16(Ag1 + kt, AsW1);
    glds16(Bg0 + kt, BsW0);
    if (BN == 128) glds16(Bg1 + kt, BsW1);
    __syncthreads();
    bf16x8 af[RT], bf[4];
#pragma unroll
    for (int i = 0; i < RT; i++) af[i] = *(const bf16x8*)(aRd + i * 16 * 32);
#pragma unroll
    for (int j = 0; j < 4; j++) bf[j] = *(const bf16x8*)(bRd + j * 16 * 32);
#pragma unroll
    for (int rt = 0; rt < RT; rt++)
#pragma unroll
      for (int ct = 0; ct < 4; ct++)
        acc[rt][ct] = __builtin_amdgcn_mfma_f32_16x16x32_bf16(af[rt], bf[ct], acc[rt][ct], 0, 0, 0);
    __syncthreads();
  }

  if (EPI == EPI_SCALE || EPI == EPI_GELU || (EPI == EPI_QKV8 && blockIdx.z < 2)) {
    short* C = (short*)outp + (long)z * czl;
#pragma unroll
    for (int ct = 0; ct < 4; ct++) {
      const int col = bn0 + wn * 64 + ct * 16 + llo;
      const float bval = (EPI == EPI_SCALE) ? 0.0f : bias[col];
#pragma unroll
      for (int rt = 0; rt < RT; rt++) {
#pragma unroll
        for (int r = 0; r < 4; r++) {
          const int row = bm0 + wm * WH + rt * 16 + lhi * 4 + r;
          float v = acc[rt][ct][r];
          if (EPI == EPI_SCALE) v *= scale;
          else v += bval;
          if (EPI == EPI_GELU) v = 0.5f * v * (1.0f + erff(v * 0.70710678118654752f));
          C[(long)row * ldc + col] = f2bs(v);
        }
      }
    }
  } else if (EPI == EPI_QKV8) {
    // z==2: V8 projection; write transposed V8T[(b*8+head)][g][s] via LDS.
    short* Ts = smem;  // [col][row], stride 136
#pragma unroll
    for (int ct = 0; ct < 4; ct++) {
      const int c = wn * 64 + ct * 16 + llo;
      const float bval = bias[bn0 + c];
#pragma unroll
      for (int rt = 0; rt < RT; rt++) {
#pragma unroll
        for (int r = 0; r < 4; r++) {
          const int row = wm * WH + rt * 16 + lhi * 4 + r;
          Ts[c * 136 + row] = f2bs(acc[rt][ct][r] + bval);
        }
      }
    }
    __syncthreads();
    const int bb = bm0 >> 10, s0 = bm0 & 1023, head = bn0 >> 7;
    short* dstbase = (short*)aux + ((long)(bb * 8 + head)) * 131072 + s0;
    const int sc8 = (t & 15) << 3;
    const int cb = t >> 4;
#pragma unroll
    for (int j = 0; j < 8; j++) {
      const int c = cb + j * 16;      // g index 0..127
      *(short8*)(dstbase + (long)c * 1024 + sc8) = *(const short8*)&Ts[c * 136 + sc8];
    }
  } else if (EPI == EPI_FFN2) {
    float* C = (float*)outp;
    const float* x1p = (const float*)aux;
#pragma unroll
    for (int ct = 0; ct < 4; ct++) {
      const int col = bn0 + wn * 64 + ct * 16 + llo;
      const float bval = bias[col];
#pragma unroll
      for (int rt = 0; rt < RT; rt++) {
#pragma unroll
        for (int r = 0; r < 4; r++) {
          const int row = bm0 + wm * WH + rt * 16 + lhi * 4 + r;
          C[(long)row * ldc + col] = acc[rt][ct][r] + bval + x1p[(long)row * ldc + col];
        }
      }
    }
  }
}

// ---------- launch ----------
extern "C" void kernel_launch(void* const* d_in, const int* in_sizes, int n_in,
                              void* d_out, int out_size, void* d_ws, size_t ws_size,
                              hipStream_t stream) {
  const float* x   = (const float*)d_in[0];
  // d_in[1] = mask (int32) — unused in infer path
  const float* g1  = (const float*)d_in[2];
  const float* b1  = (const float*)d_in[3];
  const float* Wq  = (const float*)d_in[4];
  const float* bq  = (const float*)d_in[5];
  const float* Wk  = (const float*)d_in[6];
  const float* bk  = (const float*)d_in[7];
  const float* Wv  = (const float*)d_in[8];
  const float* bv  = (const float*)d_in[9];
  const float* g2  = (const float*)d_in[10];
  const float* b2  = (const float*)d_in[11];
  const float* W1  = (const float*)d_in[12];
  const float* bw1 = (const float*)d_in[13];
  const float* W2  = (const float*)d_in[14];
  const float* bw2 = (const float*)d_in[15];

  char* ws = (char*)d_ws;
  const long MB = 1024 * 1024;
  // layout (peak 73MB):
  float* bQKV = (float*)(ws);            // [3][1024] f32: bq | bk | bv8
  float* x1   = (float*)(ws + 1 * MB);   // [4096,1024] f32  [1,17)
  short* wqT  = (short*)(ws + 17 * MB);  // [17,19)
  short* wkT  = (short*)(ws + 19 * MB);  // [19,21)  contiguous with wqT
  short* wv8T = (short*)(ws + 21 * MB);  // [21,23)  contiguous (z*1MB shorts)
  short* xn   = (short*)(ws + 23 * MB);  // [23,31)
  short* Q    = (short*)(ws + 31 * MB);  // [31,39)
  short* Kb   = (short*)(ws + 39 * MB);  // [39,47)  contiguous with Q
  short* V8T  = (short*)(ws + 47 * MB);  // [32][128][1024] bf16 [47,55)
  // FFN overlay (attention scratch dead by then):
  short* xn2  = (short*)(ws + 17 * MB);  // [17,25)
  short* Hb   = (short*)(ws + 25 * MB);  // [25,57)
  short* w1T  = (short*)(ws + 57 * MB);  // [57,65)
  short* w2T  = (short*)(ws + 65 * MB);  // [65,73)

  // stage biases: [bq; bk; bv8]
  hipMemcpyAsync(bQKV, bq, 4096, hipMemcpyDeviceToDevice, stream);
  hipMemcpyAsync(bQKV + 1024, bk, 4096, hipMemcpyDeviceToDevice, stream);
  bv8_k<<<4, 256, 0, stream>>>(bv, bQKV + 2048);

  transpose_k<<<dim3(16, 16), 256, 0, stream>>>(Wq, wqT, 1024, 1024);
  transpose_k<<<dim3(16, 16), 256, 0, stream>>>(Wk, wkT, 1024, 1024);
  wv8_k<<<dim3(16, 16), 256, 0, stream>>>(Wv, wv8T);

  ln_k<<<4096, 256, 0, stream>>>(x, g1, b1, xn);

  // Q (z=0), K (z=1) -> Q/Kb; V8 (z=2) -> V8T transposed
  gemm128<EPI_QKV8, 128><<<dim3(8, 32, 3), 256, 0, stream>>>(
      xn, 1024, 0, 0, wqT, 1024, 0, 1048576, bQKV, 1024,
      Q, 4194304, 1024, V8T, 1024, 1.0f);

  // fused attention: scores+softmax+PV8+head-sum+residual -> x1
  flash_k<<<dim3(16, 32), 256, 0, stream>>>(Q, Kb, V8T, x, x1);

  // ---- FFN phase ----
  transpose_k<<<dim3(64, 16), 256, 0, stream>>>(W1, w1T, 1024, 4096);
  transpose_k<<<dim3(16, 64), 256, 0, stream>>>(W2, w2T, 4096, 1024);

  ln_k<<<4096, 256, 0, stream>>>(x1, g2, b2, xn2);

  gemm128<EPI_GELU, 128><<<dim3(32, 32, 1), 256, 0, stream>>>(
      xn2, 1024, 0, 0, w1T, 1024, 0, 0, bw1, 0,
      Hb, 0, 4096, nullptr, 1024, 1.0f);

  gemm128<EPI_FFN2, 64><<<dim3(16, 32, 1), 256, 0, stream>>>(
      Hb, 4096, 0, 0, w2T, 4096, 0, 0, bw2, 0,
      d_out, 0, 1024, x1, 4096, 1.0f);
}

// Round 9
// 404.133 us; speedup vs baseline: 2.2318x; 1.0372x over previous
//
#include <hip/hip_runtime.h>
#include <hip/hip_bf16.h>
#include <math.h>

// ---------- types ----------
typedef __attribute__((ext_vector_type(8))) short   short8;
typedef __attribute__((ext_vector_type(4))) short   short4v;
typedef __attribute__((ext_vector_type(8))) __bf16  bf16x8;
typedef __attribute__((ext_vector_type(4))) float   f32x4;

typedef const __attribute__((address_space(1))) void cgv_t;
typedef __attribute__((address_space(3))) void lv_t;

__device__ __forceinline__ float bs2f(short s) {
  unsigned int u = ((unsigned int)(unsigned short)s) << 16;
  return __builtin_bit_cast(float, u);
}
__device__ __forceinline__ short f2bs(float f) {
  __hip_bfloat16 h = __float2bfloat16(f);  // RNE
  return __builtin_bit_cast(short, h);
}
// async global->LDS, 16B per lane; lds base must be wave-uniform
__device__ __forceinline__ void glds16(const short* g, short* l) {
  __builtin_amdgcn_global_load_lds((cgv_t*)g, (lv_t*)l, 16, 0, 0);
}

// B=4, S=1024, D=1024, H=8, FF=4096, DK=128. I/O f32; internals bf16.
// Head-sum trick: attn[s,g] = sum_k P[s,k] * V8[k,g], V8 = xn @ Wv8,
// Wv8[:,r] = sum_{e<8} Wv[:,8r+e]. Attention fused flash-style.
// Reference's raw reshape: (b,h,s,gg) attn value lands at x1 flat index
// ((b*8+h)*1024+s)*128+gg (verified round 6/8).

// ---------- weight transpose + f32->bf16: out[C][R] = bf16(in[R][C]) ----------
__global__ __launch_bounds__(256) void transpose_k(const float* __restrict__ in,
                                                   short* __restrict__ out,
                                                   int R, int C) {
  __shared__ __align__(16) short T[64 * 72];
  const int r0 = blockIdx.y * 64, c0 = blockIdx.x * 64;
  const int t = threadIdx.x;
  {
    const int rr = t >> 4;           // 0..15
    const int cc = (t & 15) << 2;    // 0..60 step 4
#pragma unroll
    for (int h = 0; h < 4; h++) {
      const int row = rr + h * 16;
      f32x4 v = *(const f32x4*)(in + (long)(r0 + row) * C + c0 + cc);
#pragma unroll
      for (int e = 0; e < 4; e++) T[row * 72 + cc + e] = f2bs(v[e]);
    }
  }
  __syncthreads();
  {
    const int cr = t >> 3;           // 0..31
    const int rs = (t & 7) << 3;     // 0..56 step 8
#pragma unroll
    for (int h = 0; h < 2; h++) {
      const int c = cr + h * 32;
      short8 v;
#pragma unroll
      for (int e = 0; e < 8; e++) v[e] = T[(rs + e) * 72 + c];
      *(short8*)(out + (long)(c0 + c) * R + r0 + rs) = v;
    }
  }
}

// ---------- wv8T[r][k] = bf16( sum_{e<8} Wv[k][8r+e] ) ----------
__global__ __launch_bounds__(256) void wv8_k(const float* __restrict__ Wv,
                                             short* __restrict__ out) {
  __shared__ __align__(16) short T[64 * 72];
  const int r0 = blockIdx.x * 64, k0 = blockIdx.y * 64;
  const int t = threadIdx.x;
  const int wave = t >> 6, lane = t & 63;
  const int r = r0 + lane;
#pragma unroll 4
  for (int i = 0; i < 16; i++) {
    const int k = k0 + wave * 16 + i;
    const float* src = Wv + (long)k * 8192 + 8 * r;
    f32x4 a = *(const f32x4*)src;
    f32x4 b = *(const f32x4*)(src + 4);
    float s = (a[0] + a[1] + a[2] + a[3]) + (b[0] + b[1] + b[2] + b[3]);
    T[lane * 72 + wave * 16 + i] = f2bs(s);
  }
  __syncthreads();
  const int rr = t >> 3, kc = (t & 7) << 3;
#pragma unroll
  for (int half = 0; half < 2; half++) {
    const int rl = rr + half * 32;
    *(short8*)(out + (long)(r0 + rl) * 1024 + k0 + kc) = *(const short8*)&T[rl * 72 + kc];
  }
}

// ---------- bv8[r] = sum_{e<8} bv[8r+e] ----------
__global__ __launch_bounds__(256) void bv8_k(const float* __restrict__ bv,
                                             float* __restrict__ out) {
  const int r = blockIdx.x * 256 + threadIdx.x;
  f32x4 a = *(const f32x4*)(bv + 8 * r);
  f32x4 b = *(const f32x4*)(bv + 8 * r + 4);
  out[r] = (a[0] + a[1] + a[2] + a[3]) + (b[0] + b[1] + b[2] + b[3]);
}

// ---------- layernorm rows of 1024; f32 in/params; bf16 out ----------
__global__ __launch_bounds__(256) void ln_k(const float* __restrict__ in,
                                            const float* __restrict__ g,
                                            const float* __restrict__ b,
                                            short* __restrict__ out) {
  const int t = threadIdx.x;
  const long base = (long)blockIdx.x * 1024 + t * 4;
  f32x4 f = *(const f32x4*)(in + base);
  float v[4] = {f[0], f[1], f[2], f[3]};
  float s1 = v[0] + v[1] + v[2] + v[3];
  float s2 = v[0]*v[0] + v[1]*v[1] + v[2]*v[2] + v[3]*v[3];
#pragma unroll
  for (int off = 32; off; off >>= 1) {
    s1 += __shfl_xor(s1, off);
    s2 += __shfl_xor(s2, off);
  }
  __shared__ float rs[4], rq[4];
  if ((t & 63) == 0) { rs[t >> 6] = s1; rq[t >> 6] = s2; }
  __syncthreads();
  s1 = rs[0] + rs[1] + rs[2] + rs[3];
  s2 = rq[0] + rq[1] + rq[2] + rq[3];
  const float mean = s1 * (1.0f / 1024.0f);
  const float var  = s2 * (1.0f / 1024.0f) - mean * mean;
  const float rstd = rsqrtf(var + 1e-5f);
  f32x4 gv = *(const f32x4*)(g + t * 4);
  f32x4 bv = *(const f32x4*)(b + t * 4);
  short4v o;
#pragma unroll
  for (int i = 0; i < 4; i++)
    o[i] = f2bs((v[i] - mean) * rstd * gv[i] + bv[i]);
  *(short4v*)(out + base) = o;
}

// ---------- split-K reduce: d_out = p0 + p1 + bias + x1 ----------
__global__ __launch_bounds__(256) void reduce2_k(const float* __restrict__ p0,
                                                 const float* __restrict__ p1,
                                                 const float* __restrict__ x1,
                                                 const float* __restrict__ bias,
                                                 float* __restrict__ out) {
  const int t = threadIdx.x;
  const long base = (long)blockIdx.x * 1024 + t * 4;
  f32x4 a = *(const f32x4*)(p0 + base);
  f32x4 b = *(const f32x4*)(p1 + base);
  f32x4 c = *(const f32x4*)(x1 + base);
  f32x4 d = *(const f32x4*)(bias + t * 4);
  *(f32x4*)(out + base) = a + b + c + d;
}

// ---------- fused flash attention (+head-sum + residual) ----------
__global__ __launch_bounds__(256, 2) void flash_k(
    const short* __restrict__ Qg_, const short* __restrict__ Kg_,
    const short* __restrict__ V8T, const float* __restrict__ xg,
    float* __restrict__ x1) {
  __shared__ __align__(16) short smem[40960];  // 80 KB exactly
  short* Qs = smem;            // 4 * [64][32]  (slab 2048 shorts)
  short* Ks = smem + 8192;     // 4 * [128][32] (slab 4096); P reuses rows 0..63
  short* Vs = smem + 24576;    // 4 * [128][32]

  const int t = threadIdx.x;
  const int wave = t >> 6, lane = t & 63;
  const int llo = lane & 15, lhi = lane >> 4;
  const int q0 = blockIdx.x * 64;
  const int bh = blockIdx.y, b = bh >> 3, h = bh & 7;
  const float SC = 0.0883883476483184f;  // 1/sqrt(128)

  const short* Qg = Qg_ + ((long)(b * 1024 + q0)) * 1024 + h * 128;
  const short* Kg = Kg_ + ((long)b * 1024) * 1024 + h * 128;
  const short* Vg = V8T + (long)bh * 131072;   // [128 g][1024 s]

  const int srow = t >> 2, schunk = (t & 3) << 3;
  const int wbase = wave * 512;          // wave-uniform stage base (shorts)
  const int arow = (wave * 16 + llo) * 32 + lhi * 8;

#pragma unroll
  for (int kk = 0; kk < 4; kk++)
    glds16(Qg + (long)srow * 1024 + kk * 32 + schunk, Qs + kk * 2048 + wbase);

  f32x4 o[8];
  float mR[4], lR[4];
#pragma unroll
  for (int i = 0; i < 8; i++) o[i] = f32x4{0.f, 0.f, 0.f, 0.f};
#pragma unroll
  for (int r = 0; r < 4; r++) { mR[r] = -1e30f; lR[r] = 0.f; }

  for (int it = 0; it < 8; it++) {
    const int kt0 = it * 128;
#pragma unroll
    for (int kk = 0; kk < 4; kk++) {
      glds16(Kg + (long)(kt0 + srow) * 1024 + kk * 32 + schunk,
             Ks + kk * 4096 + wbase);
      glds16(Kg + (long)(kt0 + 64 + srow) * 1024 + kk * 32 + schunk,
             Ks + kk * 4096 + 2048 + wbase);
      glds16(Vg + (long)srow * 1024 + kt0 + kk * 32 + schunk,
             Vs + kk * 4096 + wbase);
      glds16(Vg + (long)(64 + srow) * 1024 + kt0 + kk * 32 + schunk,
             Vs + kk * 4096 + 2048 + wbase);
    }
    __syncthreads();

    f32x4 s[8];
#pragma unroll
    for (int i = 0; i < 8; i++) s[i] = f32x4{0.f, 0.f, 0.f, 0.f};
#pragma unroll
    for (int kk = 0; kk < 4; kk++) {
      bf16x8 aq = *(const bf16x8*)(Qs + kk * 2048 + arow);
#pragma unroll
      for (int ct = 0; ct < 8; ct++) {
        bf16x8 bk = *(const bf16x8*)(Ks + kk * 4096 + (ct * 16 + llo) * 32 + lhi * 8);
        s[ct] = __builtin_amdgcn_mfma_f32_16x16x32_bf16(aq, bk, s[ct], 0, 0, 0);
      }
    }
#pragma unroll
    for (int ct = 0; ct < 8; ct++)
#pragma unroll
      for (int r = 0; r < 4; r++) s[ct][r] *= SC;
    float alpha[4];
#pragma unroll
    for (int r = 0; r < 4; r++) {
      float mt = s[0][r];
#pragma unroll
      for (int ct = 1; ct < 8; ct++) mt = fmaxf(mt, s[ct][r]);
      mt = fmaxf(mt, __shfl_xor(mt, 1));
      mt = fmaxf(mt, __shfl_xor(mt, 2));
      mt = fmaxf(mt, __shfl_xor(mt, 4));
      mt = fmaxf(mt, __shfl_xor(mt, 8));
      const float mn = fmaxf(mR[r], mt);
      alpha[r] = expf(mR[r] - mn);
      mR[r] = mn;
    }
#pragma unroll
    for (int ct = 0; ct < 8; ct++)
#pragma unroll
      for (int r = 0; r < 4; r++) s[ct][r] = expf(s[ct][r] - mR[r]);
#pragma unroll
    for (int ct = 0; ct < 8; ct++)
#pragma unroll
      for (int r = 0; r < 4; r++) o[ct][r] *= alpha[r];
#pragma unroll
    for (int r = 0; r < 4; r++) {
      float ls = s[0][r];
#pragma unroll
      for (int ct = 1; ct < 8; ct++) ls += s[ct][r];
      ls += __shfl_xor(ls, 1);
      ls += __shfl_xor(ls, 2);
      ls += __shfl_xor(ls, 4);
      ls += __shfl_xor(ls, 8);
      lR[r] = lR[r] * alpha[r] + ls;
    }
    __syncthreads();

#pragma unroll
    for (int ct = 0; ct < 8; ct++) {
      const int base = (ct >> 1) * 4096 + ((ct & 1) << 4) + llo;
#pragma unroll
      for (int r = 0; r < 4; r++)
        Ks[base + (wave * 16 + lhi * 4 + r) * 32] = f2bs(s[ct][r]);
    }
    __syncthreads();

#pragma unroll
    for (int kk = 0; kk < 4; kk++) {
      bf16x8 ap = *(const bf16x8*)(Ks + kk * 4096 + arow);
#pragma unroll
      for (int ct = 0; ct < 8; ct++) {
        bf16x8 bv = *(const bf16x8*)(Vs + kk * 4096 + (ct * 16 + llo) * 32 + lhi * 8);
        o[ct] = __builtin_amdgcn_mfma_f32_16x16x32_bf16(ap, bv, o[ct], 0, 0, 0);
      }
    }
    __syncthreads();
  }

  float inv[4];
#pragma unroll
  for (int r = 0; r < 4; r++) inv[r] = 1.0f / lR[r];
#pragma unroll
  for (int ct = 0; ct < 8; ct++) {
#pragma unroll
    for (int r = 0; r < 4; r++) {
      const int row = q0 + wave * 16 + lhi * 4 + r;
      const long idx = ((long)(b * 8 + h) * 1024 + row) * 128 + ct * 16 + llo;
      x1[idx] = xg[idx] + o[ct][r] * inv[r];
    }
  }
}

// ---------- 128xBN MFMA GEMM, NS k-slabs (BK=32*NS) per barrier ----------
// C[m][n] = sum_k A[m][k]*Bt[n][k]. 256 threads = 4 waves (2x2 for BN=128,
// 4x1 for BN=64). z offsets: A += (z>>3)*azh+(z&7)*azl; B likewise.
enum { EPI_GELU = 4, EPI_QKV8 = 6, EPI_PART = 8 };

template <int EPI, int BN, int NS>
__global__ __launch_bounds__(256) void gemm128(
    const short* __restrict__ A, int lda, long azh, long azl,
    const short* __restrict__ Bt, int ldb, long bzh, long bzl,
    const float* __restrict__ bias, long biasl,
    void* __restrict__ outp, long czl, int ldc,
    const void* __restrict__ aux,
    int K) {
  constexpr int WH = (BN == 128) ? 64 : 32;   // rows per wave
  constexpr int RT = WH / 16;                 // row frags per wave
  constexpr int ASLAB = 4096;                 // 128x32 shorts
  constexpr int BSLAB = BN * 32;
  constexpr int STAGE = NS * (ASLAB + BSLAB);
  constexpr int SMEM_SHORTS = (EPI == EPI_QKV8 && STAGE < 17408) ? 17408 : STAGE;
  __shared__ __align__(16) short smem[SMEM_SHORTS];
  short* As = smem;                 // NS slabs of [128][32]
  short* Bs = smem + NS * ASLAB;    // NS slabs of [BN][32]

  const int t = threadIdx.x;
  const int wave = t >> 6, lane = t & 63;
  const int llo = lane & 15, lhi = lane >> 4;
  const int wm = (BN == 128) ? (wave >> 1) : wave;
  const int wn = (BN == 128) ? (wave & 1) : 0;
  const int bn0 = blockIdx.x * BN, bm0 = blockIdx.y * 128;
  const int z = blockIdx.z;
  const int zh = z >> 3, zl = z & 7;

  const short* Ab = A + (long)zh * azh + (long)zl * azl;
  const short* Bb = Bt + (long)zh * bzh + (long)zl * bzl;
  bias += (long)zl * biasl;

  f32x4 acc[RT][4];
#pragma unroll
  for (int i = 0; i < RT; i++)
#pragma unroll
    for (int j = 0; j < 4; j++) acc[i][j] = f32x4{0.f, 0.f, 0.f, 0.f};

  const int srow = t >> 2, schunk = (t & 3) << 3;
  const short* Ag0 = Ab + (long)(bm0 + srow) * lda + schunk;
  const short* Ag1 = Ab + (long)(bm0 + 64 + srow) * lda + schunk;
  const short* Bg0 = Bb + (long)(bn0 + srow) * ldb + schunk;
  const short* Bg1 = Bb + (long)(bn0 + 64 + srow) * ldb + schunk;
  short* AsW0 = As + (wave * 16) * 32;        // wave-uniform bases
  short* AsW1 = As + (64 + wave * 16) * 32;
  short* BsW0 = Bs + (wave * 16) * 32;
  short* BsW1 = Bs + (64 + wave * 16) * 32;

  const short* aRd = As + (wm * WH + llo) * 32 + lhi * 8;
  const short* bRd = Bs + (wn * 64 + llo) * 32 + lhi * 8;

  for (int kt = 0; kt < K; kt += 32 * NS) {
#pragma unroll
    for (int s = 0; s < NS; s++) {
      glds16(Ag0 + kt + s * 32, AsW0 + s * ASLAB);
      glds16(Ag1 + kt + s * 32, AsW1 + s * ASLAB);
      glds16(Bg0 + kt + s * 32, BsW0 + s * BSLAB);
      if (BN == 128) glds16(Bg1 + kt + s * 32, BsW1 + s * BSLAB);
    }
    __syncthreads();   // drain glds
#pragma unroll
    for (int s = 0; s < NS; s++) {
      bf16x8 af[RT], bf[4];
#pragma unroll
      for (int i = 0; i < RT; i++)
        af[i] = *(const bf16x8*)(aRd + s * ASLAB + i * 16 * 32);
#pragma unroll
      for (int j = 0; j < 4; j++)
        bf[j] = *(const bf16x8*)(bRd + s * BSLAB + j * 16 * 32);
#pragma unroll
      for (int rt = 0; rt < RT; rt++)
#pragma unroll
        for (int ct = 0; ct < 4; ct++)
          acc[rt][ct] = __builtin_amdgcn_mfma_f32_16x16x32_bf16(af[rt], bf[ct], acc[rt][ct], 0, 0, 0);
    }
    __syncthreads();   // protect LDS before next stage
  }

  if (EPI == EPI_GELU || (EPI == EPI_QKV8 && blockIdx.z < 2)) {
    short* C = (short*)outp + (long)z * czl;
#pragma unroll
    for (int ct = 0; ct < 4; ct++) {
      const int col = bn0 + wn * 64 + ct * 16 + llo;
      const float bval = bias[col];
#pragma unroll
      for (int rt = 0; rt < RT; rt++) {
#pragma unroll
        for (int r = 0; r < 4; r++) {
          const int row = bm0 + wm * WH + rt * 16 + lhi * 4 + r;
          float v = acc[rt][ct][r] + bval;
          if (EPI == EPI_GELU) v = 0.5f * v * (1.0f + erff(v * 0.70710678118654752f));
          C[(long)row * ldc + col] = f2bs(v);
        }
      }
    }
  } else if (EPI == EPI_QKV8) {
    // z==2: V8 projection; write transposed V8T[(b*8+head)][g][s] via LDS.
    short* Ts = smem;  // [col][row], stride 136
#pragma unroll
    for (int ct = 0; ct < 4; ct++) {
      const int c = wn * 64 + ct * 16 + llo;
      const float bval = bias[bn0 + c];
#pragma unroll
      for (int rt = 0; rt < RT; rt++) {
#pragma unroll
        for (int r = 0; r < 4; r++) {
          const int row = wm * WH + rt * 16 + lhi * 4 + r;
          Ts[c * 136 + row] = f2bs(acc[rt][ct][r] + bval);
        }
      }
    }
    __syncthreads();
    const int bb = bm0 >> 10, s0 = bm0 & 1023, head = bn0 >> 7;
    short* dstbase = (short*)aux + ((long)(bb * 8 + head)) * 131072 + s0;
    const int sc8 = (t & 15) << 3;
    const int cb = t >> 4;
#pragma unroll
    for (int j = 0; j < 8; j++) {
      const int c = cb + j * 16;      // g index 0..127
      *(short8*)(dstbase + (long)c * 1024 + sc8) = *(const short8*)&Ts[c * 136 + sc8];
    }
  } else if (EPI == EPI_PART) {
    // f32 partial (no bias): P[z][row][ldc]
    float* C = (float*)outp + (long)z * czl;
#pragma unroll
    for (int ct = 0; ct < 4; ct++) {
      const int col = bn0 + wn * 64 + ct * 16 + llo;
#pragma unroll
      for (int rt = 0; rt < RT; rt++) {
#pragma unroll
        for (int r = 0; r < 4; r++) {
          const int row = bm0 + wm * WH + rt * 16 + lhi * 4 + r;
          C[(long)row * ldc + col] = acc[rt][ct][r];
        }
      }
    }
  }
}

// ---------- launch ----------
extern "C" void kernel_launch(void* const* d_in, const int* in_sizes, int n_in,
                              void* d_out, int out_size, void* d_ws, size_t ws_size,
                              hipStream_t stream) {
  const float* x   = (const float*)d_in[0];
  // d_in[1] = mask (int32) — unused in infer path
  const float* g1  = (const float*)d_in[2];
  const float* b1  = (const float*)d_in[3];
  const float* Wq  = (const float*)d_in[4];
  const float* bq  = (const float*)d_in[5];
  const float* Wk  = (const float*)d_in[6];
  const float* bk  = (const float*)d_in[7];
  const float* Wv  = (const float*)d_in[8];
  const float* bv  = (const float*)d_in[9];
  const float* g2  = (const float*)d_in[10];
  const float* b2  = (const float*)d_in[11];
  const float* W1  = (const float*)d_in[12];
  const float* bw1 = (const float*)d_in[13];
  const float* W2  = (const float*)d_in[14];
  const float* bw2 = (const float*)d_in[15];

  char* ws = (char*)d_ws;
  const long MB = 1024 * 1024;
  // layout (peak 105MB; ws >= 189MB proven in round 5):
  float* bQKV = (float*)(ws);            // [3][1024] f32: bq | bk | bv8
  float* x1   = (float*)(ws + 1 * MB);   // [4096,1024] f32  [1,17)
  short* wqT  = (short*)(ws + 17 * MB);  // [17,19)
  short* wkT  = (short*)(ws + 19 * MB);  // [19,21)  contiguous with wqT
  short* wv8T = (short*)(ws + 21 * MB);  // [21,23)  contiguous (z*1MB shorts)
  short* xn   = (short*)(ws + 23 * MB);  // [23,31)
  short* Q    = (short*)(ws + 31 * MB);  // [31,39)
  short* Kb   = (short*)(ws + 39 * MB);  // [39,47)  contiguous with Q
  short* V8T  = (short*)(ws + 47 * MB);  // [32][128][1024] bf16 [47,55)
  // FFN overlay (attention scratch dead by then):
  short* xn2  = (short*)(ws + 17 * MB);  // [17,25)
  short* Hb   = (short*)(ws + 25 * MB);  // [25,57)
  short* w1T  = (short*)(ws + 57 * MB);  // [57,65)
  short* w2T  = (short*)(ws + 65 * MB);  // [65,73)
  float* part = (float*)(ws + 73 * MB);  // [2][4096,1024] f32 [73,105)

  // stage biases: [bq; bk; bv8]
  hipMemcpyAsync(bQKV, bq, 4096, hipMemcpyDeviceToDevice, stream);
  hipMemcpyAsync(bQKV + 1024, bk, 4096, hipMemcpyDeviceToDevice, stream);
  bv8_k<<<4, 256, 0, stream>>>(bv, bQKV + 2048);

  transpose_k<<<dim3(16, 16), 256, 0, stream>>>(Wq, wqT, 1024, 1024);
  transpose_k<<<dim3(16, 16), 256, 0, stream>>>(Wk, wkT, 1024, 1024);
  wv8_k<<<dim3(16, 16), 256, 0, stream>>>(Wv, wv8T);

  ln_k<<<4096, 256, 0, stream>>>(x, g1, b1, xn);

  // Q (z=0), K (z=1) -> Q/Kb; V8 (z=2) -> V8T transposed. BK=64.
  gemm128<EPI_QKV8, 128, 2><<<dim3(8, 32, 3), 256, 0, stream>>>(
      xn, 1024, 0, 0, wqT, 1024, 0, 1048576, bQKV, 1024,
      Q, 4194304, 1024, V8T, 1024);

  // fused attention: scores+softmax+PV8+head-sum+residual -> x1
  flash_k<<<dim3(16, 32), 256, 0, stream>>>(Q, Kb, V8T, x, x1);

  // ---- FFN phase ----
  transpose_k<<<dim3(64, 16), 256, 0, stream>>>(W1, w1T, 1024, 4096);
  transpose_k<<<dim3(16, 64), 256, 0, stream>>>(W2, w2T, 4096, 1024);

  ln_k<<<4096, 256, 0, stream>>>(x1, g2, b2, xn2);

  // FFN1 + exact GELU -> Hb (bf16). BK=64.
  gemm128<EPI_GELU, 128, 2><<<dim3(32, 32, 1), 256, 0, stream>>>(
      xn2, 1024, 0, 0, w1T, 1024, 0, 0, bw1, 0,
      Hb, 0, 4096, nullptr, 1024);

  // FFN2 split-K=2: partials (f32), then reduce + bias + residual -> d_out
  gemm128<EPI_PART, 64, 2><<<dim3(16, 32, 2), 256, 0, stream>>>(
      Hb, 4096, 0, 2048, w2T, 4096, 0, 2048, nullptr, 0,
      part, 4194304, 1024, nullptr, 2048);

  reduce2_k<<<4096, 256, 0, stream>>>(part, part + 4194304, x1, bw2,
                                      (float*)d_out);
}